// Round 7
// baseline (420.241 us; speedup 1.0000x reference)
//
#include <hip/hip_runtime.h>
#include <hip/hip_bf16.h>
#include <cstdint>

// Problem constants
#define T_LEN 1024
#define HIDN  1024
#define NH    16
#define DHD   64

typedef __bf16 bf16x8 __attribute__((ext_vector_type(8)));
typedef float  f32x4  __attribute__((ext_vector_type(4)));

__device__ inline void split8(float4 x0, float4 x1, uint4& hi, uint4& lo) {
  union { __bf16 h[8]; uint4 u; } ph, pl;
  float v[8] = {x0.x, x0.y, x0.z, x0.w, x1.x, x1.y, x1.z, x1.w};
#pragma unroll
  for (int j = 0; j < 8; j++) {
    __bf16 h = (__bf16)v[j];
    ph.h[j] = h;
    pl.h[j] = (__bf16)(v[j] - (float)h);
  }
  hi = ph.u; lo = pl.u;
}

// ---------------------------------------------------------------------------
// K2: transpose 1024x1024 f32 W[k][n] -> bf16 hi/lo Wt[n][k] (5 weights via z)
// lo stored only for Wk (z=1) and Wv (z=2) — the recurrence-path weights.
// ---------------------------------------------------------------------------
__global__ __launch_bounds__(256) void k_transp_split(
    const float* __restrict__ W0, const float* __restrict__ W1,
    const float* __restrict__ W2, const float* __restrict__ W3,
    const float* __restrict__ W4,
    __bf16* __restrict__ H0, __bf16* __restrict__ H1, __bf16* __restrict__ H2,
    __bf16* __restrict__ H3, __bf16* __restrict__ H4,
    __bf16* __restrict__ L1, __bf16* __restrict__ L2) {
  const float* W; __bf16* Th; __bf16* Tl;
  switch (blockIdx.z) {
    case 0: W = W0; Th = H0; Tl = nullptr; break;
    case 1: W = W1; Th = H1; Tl = L1; break;
    case 2: W = W2; Th = H2; Tl = L2; break;
    case 3: W = W3; Th = H3; Tl = nullptr; break;
    default: W = W4; Th = H4; Tl = nullptr; break;
  }
  __shared__ float tile[64][65];
  int tid = threadIdx.x;
  int r0 = tid >> 4;          // 0..15
  int c0 = (tid & 15) * 4;    // 0..60
  int kbase = blockIdx.y * 64, nbase = blockIdx.x * 64;
#pragma unroll
  for (int rr = 0; rr < 4; rr++) {
    int r = r0 + rr * 16;
    float4 v = *(const float4*)(W + (size_t)(kbase + r) * 1024 + nbase + c0);
    tile[r][c0 + 0] = v.x; tile[r][c0 + 1] = v.y;
    tile[r][c0 + 2] = v.z; tile[r][c0 + 3] = v.w;
  }
  __syncthreads();
#pragma unroll
  for (int rr = 0; rr < 4; rr++) {
    int n = r0 + rr * 16;
    union { __bf16 h[4]; unsigned long long u; } ph, pl;
#pragma unroll
    for (int j = 0; j < 4; j++) {
      float v = tile[c0 + j][n];
      __bf16 h = (__bf16)v;
      ph.h[j] = h;
      pl.h[j] = (__bf16)(v - (float)h);
    }
    *(unsigned long long*)(Th + (size_t)(nbase + n) * 1024 + kbase + c0) = ph.u;
    if (Tl)
      *(unsigned long long*)(Tl + (size_t)(nbase + n) * 1024 + kbase + c0) = pl.u;
  }
}

// ---------------------------------------------------------------------------
// K3: split-precision GEMM, A fp32 (inline hi/lo split), B pre-split bf16.
// Per-z term count nt: 1 -> Ah*Bh ; 2 -> +Al*Bh ; 3 -> +Ah*Bl.
// 128x128 tile, BK=32, 4 waves.
// ---------------------------------------------------------------------------
#define LDT 40
__global__ __launch_bounds__(256) void k_gemm3f(
    const float* __restrict__ Af,
    const __bf16* __restrict__ Bh0, const __bf16* __restrict__ Bh1,
    const __bf16* __restrict__ Bh2, const __bf16* __restrict__ Bh3,
    const __bf16* __restrict__ Bl0, const __bf16* __restrict__ Bl1,
    const __bf16* __restrict__ Bl2, const __bf16* __restrict__ Bl3,
    float* __restrict__ C0, float* __restrict__ C1,
    float* __restrict__ C2, float* __restrict__ C3,
    int nt0, int nt1, int nt2, int nt3,
    int Kdim, int Ncols) {
  const __bf16* Bh; const __bf16* Bl; float* C; int nt;
  switch (blockIdx.z) {
    case 0: Bh = Bh0; Bl = Bl0; C = C0; nt = nt0; break;
    case 1: Bh = Bh1; Bl = Bl1; C = C1; nt = nt1; break;
    case 2: Bh = Bh2; Bl = Bl2; C = C2; nt = nt2; break;
    default: Bh = Bh3; Bl = Bl3; C = C3; nt = nt3; break;
  }
  __shared__ __bf16 Ash[128 * LDT];
  __shared__ __bf16 Asl[128 * LDT];
  __shared__ __bf16 Bsh[128 * LDT];
  __shared__ __bf16 Bsl[128 * LDT];
  const int tid = threadIdx.x;
  const int lane = tid & 63;
  const int wave = tid >> 6;
  const int wr = wave >> 1, wc = wave & 1;
  const int rowA0 = blockIdx.y * 128;
  const int colB0 = blockIdx.x * 128;
  const int sseg = tid & 3;
  const int srow0 = tid >> 2;
  const int srow1 = srow0 + 64;

  f32x4 acc[4][4] = {};

  for (int k0 = 0; k0 < Kdim; k0 += 32) {
    size_t a0 = (size_t)(rowA0 + srow0) * Kdim + k0 + sseg * 8;
    size_t a1 = (size_t)(rowA0 + srow1) * Kdim + k0 + sseg * 8;
    size_t b0 = (size_t)(colB0 + srow0) * Kdim + k0 + sseg * 8;
    size_t b1 = (size_t)(colB0 + srow1) * Kdim + k0 + sseg * 8;
    float4 a00 = *(const float4*)(Af + a0);
    float4 a01 = *(const float4*)(Af + a0 + 4);
    float4 a10 = *(const float4*)(Af + a1);
    float4 a11 = *(const float4*)(Af + a1 + 4);
    uint4 rbh0 = *(const uint4*)(Bh + b0);
    uint4 rbh1 = *(const uint4*)(Bh + b1);
    uint4 rbl0, rbl1;
    if (nt >= 3) {
      rbl0 = *(const uint4*)(Bl + b0);
      rbl1 = *(const uint4*)(Bl + b1);
    }
    uint4 rah0, ral0, rah1, ral1;
    split8(a00, a01, rah0, ral0);
    split8(a10, a11, rah1, ral1);
    __syncthreads();
    *(uint4*)&Ash[srow0 * LDT + sseg * 8] = rah0;
    *(uint4*)&Ash[srow1 * LDT + sseg * 8] = rah1;
    if (nt >= 2) {
      *(uint4*)&Asl[srow0 * LDT + sseg * 8] = ral0;
      *(uint4*)&Asl[srow1 * LDT + sseg * 8] = ral1;
    }
    *(uint4*)&Bsh[srow0 * LDT + sseg * 8] = rbh0;
    *(uint4*)&Bsh[srow1 * LDT + sseg * 8] = rbh1;
    if (nt >= 3) {
      *(uint4*)&Bsl[srow0 * LDT + sseg * 8] = rbl0;
      *(uint4*)&Bsl[srow1 * LDT + sseg * 8] = rbl1;
    }
    __syncthreads();
    bf16x8 afh[4], afl[4], bfh[4], bfl[4];
#pragma unroll
    for (int mi = 0; mi < 4; mi++) {
      int off = (wr * 64 + mi * 16 + (lane & 15)) * LDT + (lane >> 4) * 8;
      afh[mi] = *(const bf16x8*)&Ash[off];
      if (nt >= 2) afl[mi] = *(const bf16x8*)&Asl[off];
    }
#pragma unroll
    for (int ni = 0; ni < 4; ni++) {
      int off = (wc * 64 + ni * 16 + (lane & 15)) * LDT + (lane >> 4) * 8;
      bfh[ni] = *(const bf16x8*)&Bsh[off];
      if (nt >= 3) bfl[ni] = *(const bf16x8*)&Bsl[off];
    }
#pragma unroll
    for (int mi = 0; mi < 4; mi++)
#pragma unroll
      for (int ni = 0; ni < 4; ni++) {
        acc[mi][ni] = __builtin_amdgcn_mfma_f32_16x16x32_bf16(afh[mi], bfh[ni], acc[mi][ni], 0, 0, 0);
        if (nt >= 2)
          acc[mi][ni] = __builtin_amdgcn_mfma_f32_16x16x32_bf16(afl[mi], bfh[ni], acc[mi][ni], 0, 0, 0);
        if (nt >= 3)
          acc[mi][ni] = __builtin_amdgcn_mfma_f32_16x16x32_bf16(afh[mi], bfl[ni], acc[mi][ni], 0, 0, 0);
      }
  }
#pragma unroll
  for (int mi = 0; mi < 4; mi++)
#pragma unroll
    for (int ni = 0; ni < 4; ni++) {
      int col = colB0 + wc * 64 + ni * 16 + (lane & 15);
#pragma unroll
      for (int r = 0; r < 4; r++) {
        int row = rowA0 + wr * 64 + mi * 16 + (lane >> 4) * 4 + r;
        C[(size_t)row * Ncols + col] = acc[mi][ni][r];
      }
    }
}

// ---------------------------------------------------------------------------
// K_CRA: fused gates + causal dwconv(K=4)+SiLU -> RoPE -> L2 norm -> aux pack.
// One wave per (bt,h); lane = channel-within-head d.
// Gates: d1 = x_row . bw[:,h], d2 = x_row . gkw[:,h] via per-lane partials +
// wave reduce; beta/alpha computed in-wave (no separate k_gates kernel).
// ---------------------------------------------------------------------------
__global__ __launch_bounds__(256) void k_cra(
    const float* __restrict__ qp, const float* __restrict__ kp,
    const float* __restrict__ vp, const float* __restrict__ x,
    const float* __restrict__ qcw, const float* __restrict__ qcb,
    const float* __restrict__ kcw, const float* __restrict__ kcb,
    const float* __restrict__ vcw, const float* __restrict__ vcb,
    const float* __restrict__ bw, const float* __restrict__ bb,
    const float* __restrict__ gkw, const float* __restrict__ gkb,
    const float* __restrict__ A_log, const float* __restrict__ dtb,
    const float* __restrict__ Dp,
    float* __restrict__ qr, float* __restrict__ kr, float* __restrict__ vr,
    float4* __restrict__ aux) {
  int widx = blockIdx.x * 4 + (threadIdx.x >> 6);
  int lane = threadIdx.x & 63;
  int h = widx & 15;
  int bt = widx >> 4;
  int t = bt & 1023, b = bt >> 10;
  int c = h * 64 + lane;
  size_t colbase = ((size_t)b * 1024) * 1024 + c;

  // ---- gates ----
  const float* xr = x + (size_t)bt * HIDN;
  float d1 = 0.f, d2 = 0.f;
#pragma unroll
  for (int j = 0; j < 16; j++) {
    int k = lane + j * 64;
    float xv = xr[k];
    d1 += xv * bw[k * 16 + h];
    d2 += xv * gkw[k * 16 + h];
  }
#pragma unroll
  for (int m = 1; m < 64; m <<= 1) { d1 += __shfl_xor(d1, m); d2 += __shfl_xor(d2, m); }
  float beta = 1.f / (1.f + expf(-(d1 + bb[h])));
  float z2 = d2 + gkb[h] + dtb[h];
  float sp = fmaxf(z2, 0.f) + log1pf(expf(-fabsf(z2)));
  float alpha = expf(-expf(A_log[h]) * sp);

  // ---- conv + silu for q, k, v ----
  float4 wq = *(const float4*)(qcw + (size_t)c * 4);
  float4 wk = *(const float4*)(kcw + (size_t)c * 4);
  float4 wv = *(const float4*)(vcw + (size_t)c * 4);
  float aq = qcb[c], ak = kcb[c], av = vcb[c];
  {
    float x0 = qp[colbase + (size_t)t * 1024];
    float y0 = kp[colbase + (size_t)t * 1024];
    float z0 = vp[colbase + (size_t)t * 1024];
    aq += wq.w * x0; ak += wk.w * y0; av += wv.w * z0;
    if (t >= 1) {
      float x1 = qp[colbase + (size_t)(t - 1) * 1024];
      float y1 = kp[colbase + (size_t)(t - 1) * 1024];
      float z1 = vp[colbase + (size_t)(t - 1) * 1024];
      aq += wq.z * x1; ak += wk.z * y1; av += wv.z * z1;
    }
    if (t >= 2) {
      float x2 = qp[colbase + (size_t)(t - 2) * 1024];
      float y2 = kp[colbase + (size_t)(t - 2) * 1024];
      float z2v = vp[colbase + (size_t)(t - 2) * 1024];
      aq += wq.y * x2; ak += wk.y * y2; av += wv.y * z2v;
    }
    if (t >= 3) {
      float x3 = qp[colbase + (size_t)(t - 3) * 1024];
      float y3 = kp[colbase + (size_t)(t - 3) * 1024];
      float z3 = vp[colbase + (size_t)(t - 3) * 1024];
      aq += wq.x * x3; ak += wk.x * y3; av += wv.x * z3;
    }
  }
  float yq = aq / (1.f + expf(-aq));
  float yk = ak / (1.f + expf(-ak));
  float yv = av / (1.f + expf(-av));

  // ---- rope ----
  int i = lane & 31;
  float fr = expf(-(float)(2 * (i & 15)) * (9.210340371976184f / 32.f));
  float ang = (float)t * fr;
  float cv = cosf(ang), sv = sinf(ang);
  float q1 = __shfl(yq, 2 * i), q2 = __shfl(yq, 2 * i + 1);
  float k1 = __shfl(yk, 2 * i), k2 = __shfl(yk, 2 * i + 1);
  float qo = (lane < 32) ? (q1 * cv - q2 * sv) : (q1 * sv + q2 * cv);
  float ko = (lane < 32) ? (k1 * cv - k2 * sv) : (k1 * sv + k2 * cv);

  // ---- L2 norm + aux ----
  float qs = qo * qo, ks2 = ko * ko;
#pragma unroll
  for (int m = 1; m < 64; m <<= 1) { qs += __shfl_xor(qs, m); ks2 += __shfl_xor(ks2, m); }
  float qn = qo * rsqrtf(qs + 1e-6f);
  float kn = ko * rsqrtf(ks2 + 1e-6f);
  float dq = qn * kn;
#pragma unroll
  for (int m = 1; m < 64; m <<= 1) dq += __shfl_xor(dq, m);
  size_t obase = ((size_t)(b * 16 + h) * 1024 + t) * 64;
  qr[obase + lane] = qn;
  kr[obase + lane] = kn;
  vr[obase + lane] = yv;
  if (lane == 0)
    aux[(size_t)(b * 16 + h) * 1024 + t] = make_float4(alpha, beta, alpha * beta, Dp[h] * dq);
}

// ---------------------------------------------------------------------------
// K8a: WY-form scan, S0-independent per-chunk work (unchanged math).
// ---------------------------------------------------------------------------
__global__ __launch_bounds__(128) void k_scanA(
    const float* __restrict__ qr, const float* __restrict__ kr,
    const float* __restrict__ vr, const float4* __restrict__ aux,
    float* __restrict__ O1, float* __restrict__ AcF,
    float* __restrict__ BcTF, float* __restrict__ QeffF,
    float* __restrict__ gcF) {
  const int bid = blockIdx.x;
  const int bh = bid >> 4, c = bid & 15;
  const int t0 = c * 64;
  const int tid = threadIdx.x;
  const int w = tid >> 6, lane = tid & 63;
  const float* qB = qr + (size_t)bh * 65536 + (size_t)t0 * 64;
  const float* kB = kr + (size_t)bh * 65536 + (size_t)t0 * 64;
  const float* vB = vr + (size_t)bh * 65536 + (size_t)t0 * 64;
  const float4* auxB = aux + (size_t)bh * T_LEN + t0;

  __shared__ __bf16 q_b[64 * 72];
  __shared__ __bf16 k_b[64 * 72];
  __shared__ __bf16 kT_b[64 * 72];
  __shared__ __bf16 C_b[64 * 72];
  __shared__ __bf16 U0T[64 * 72];
  __shared__ __bf16 WT[64 * 72];
  __shared__ float  vS[64 * 64];
  __shared__ float  MTf[64 * 68];
  __shared__ float  lgS[64], pvS[64], beS[64], awS[64], enS[64];

  if (w == 0) {
    float4 a4 = auxB[lane];
    float lg = logf(a4.x);
#pragma unroll
    for (int off = 1; off < 64; off <<= 1) {
      float tv = __shfl_up(lg, off);
      if (lane >= off) lg += tv;
    }
    float pv = __shfl_up(lg, 1);
    if (lane == 0) pv = 0.f;
    float lgTot = __shfl(lg, 63);
    lgS[lane] = lg; pvS[lane] = pv; beS[lane] = a4.y; awS[lane] = a4.w;
    enS[lane] = expf(lgTot - lg);
    if (lane == 0) gcF[bid] = expf(lgTot);
  }
#pragma unroll
  for (int p = 0; p < 4; p++) {
    int s = p * 128 + tid;
    int row = s >> 3, col8 = s & 7;
    const float* gq = qB + (size_t)row * 64 + col8 * 8;
    const float* gk = kB + (size_t)row * 64 + col8 * 8;
    const float* gv = vB + (size_t)row * 64 + col8 * 8;
    float4 q0 = *(const float4*)gq, q1 = *(const float4*)(gq + 4);
    float4 k0 = *(const float4*)gk, k1 = *(const float4*)(gk + 4);
    float4 v0 = *(const float4*)gv, v1 = *(const float4*)(gv + 4);
    union { __bf16 h[8]; uint4 u; } pq, pk;
    pq.h[0] = (__bf16)q0.x; pq.h[1] = (__bf16)q0.y; pq.h[2] = (__bf16)q0.z; pq.h[3] = (__bf16)q0.w;
    pq.h[4] = (__bf16)q1.x; pq.h[5] = (__bf16)q1.y; pq.h[6] = (__bf16)q1.z; pq.h[7] = (__bf16)q1.w;
    pk.h[0] = (__bf16)k0.x; pk.h[1] = (__bf16)k0.y; pk.h[2] = (__bf16)k0.z; pk.h[3] = (__bf16)k0.w;
    pk.h[4] = (__bf16)k1.x; pk.h[5] = (__bf16)k1.y; pk.h[6] = (__bf16)k1.z; pk.h[7] = (__bf16)k1.w;
    *(uint4*)&q_b[row * 72 + col8 * 8] = pq.u;
    *(uint4*)&k_b[row * 72 + col8 * 8] = pk.u;
    *(float4*)&vS[row * 64 + col8 * 8] = v0;
    *(float4*)&vS[row * 64 + col8 * 8 + 4] = v1;
  }
  __syncthreads();

#pragma unroll
  for (int mm = 0; mm < 2; mm++) {
    int mi = w * 2 + mm;
#pragma unroll
    for (int ni = 0; ni < 4; ni++) {
      f32x4 akk = {0.f, 0.f, 0.f, 0.f};
      f32x4 aqk = {0.f, 0.f, 0.f, 0.f};
#pragma unroll
      for (int ks = 0; ks < 2; ks++) {
        bf16x8 fa_k = *(const bf16x8*)&k_b[(mi * 16 + (lane & 15)) * 72 + ks * 32 + (lane >> 4) * 8];
        bf16x8 fa_q = *(const bf16x8*)&q_b[(mi * 16 + (lane & 15)) * 72 + ks * 32 + (lane >> 4) * 8];
        bf16x8 fb_k = *(const bf16x8*)&k_b[(ni * 16 + (lane & 15)) * 72 + ks * 32 + (lane >> 4) * 8];
        akk = __builtin_amdgcn_mfma_f32_16x16x32_bf16(fa_k, fb_k, akk, 0, 0, 0);
        aqk = __builtin_amdgcn_mfma_f32_16x16x32_bf16(fa_q, fb_k, aqk, 0, 0, 0);
      }
#pragma unroll
      for (int r = 0; r < 4; r++) {
        int row = mi * 16 + (lane >> 4) * 4 + r;
        int col = ni * 16 + (lane & 15);
        float mt = 0.f, cv = 0.f;
        if (row > col) {
          mt = beS[row] * expf(lgS[row] - lgS[col]) * akk[r];
          cv = expf(pvS[row] - lgS[col]) * aqk[r];
        }
        MTf[col * 68 + row] = mt;
        C_b[row * 72 + col] = (__bf16)cv;
      }
    }
  }
  __syncthreads();

  if (w == 1) {
#pragma unroll
    for (int t8 = 0; t8 < 8; t8++) {
      union { __bf16 h[8]; uint4 u; } pt;
#pragma unroll
      for (int q = 0; q < 8; q++) {
        int t = t8 * 8 + q;
        pt.h[q] = (__bf16)((float)k_b[t * 72 + lane] * enS[t]);
      }
      *(uint4*)&kT_b[lane * 72 + t8 * 8] = pt.u;
    }
  }

  {
    float u[64];
    if (w == 0) {
#pragma unroll
      for (int j = 0; j < 64; j++) u[j] = beS[j] * vS[j * 64 + lane];
    } else {
#pragma unroll
      for (int j = 0; j < 64; j++) u[j] = beS[j] * expf(lgS[j]) * (float)k_b[j * 72 + lane];
    }
    __bf16* dst = (w == 0) ? U0T : WT;
#pragma unroll
    for (int j = 0; j < 64; j++) {
      dst[lane * 72 + j] = (__bf16)u[j];
      float uj = u[j];
#pragma unroll
      for (int g = (j >> 4); g < 4; g++) {
#pragma unroll
        for (int q4 = 0; q4 < 4; q4++) {
          const float4 m4 = *(const float4*)&MTf[j * 68 + g * 16 + q4 * 4];
          u[g * 16 + q4 * 4 + 0] -= m4.x * uj;
          u[g * 16 + q4 * 4 + 1] -= m4.y * uj;
          u[g * 16 + q4 * 4 + 2] -= m4.z * uj;
          u[g * 16 + q4 * 4 + 3] -= m4.w * uj;
        }
      }
    }
  }
  __syncthreads();

  size_t cb = (size_t)bid * 4096;
  if (w == 0) {
#pragma unroll
    for (int mi = 0; mi < 4; mi++)
#pragma unroll
      for (int ni = 0; ni < 4; ni++) {
        f32x4 ab = {0.f, 0.f, 0.f, 0.f};
        f32x4 aa = {0.f, 0.f, 0.f, 0.f};
#pragma unroll
        for (int ks = 0; ks < 2; ks++) {
          int aoff = (mi * 16 + (lane & 15)) * 72 + ks * 32 + (lane >> 4) * 8;
          int boff = (ni * 16 + (lane & 15)) * 72 + ks * 32 + (lane >> 4) * 8;
          bf16x8 fu = *(const bf16x8*)&U0T[aoff];
          bf16x8 fkm = *(const bf16x8*)&kT_b[aoff];
          bf16x8 fkn = *(const bf16x8*)&kT_b[boff];
          bf16x8 fw = *(const bf16x8*)&WT[boff];
          ab = __builtin_amdgcn_mfma_f32_16x16x32_bf16(fu, fkn, ab, 0, 0, 0);
          aa = __builtin_amdgcn_mfma_f32_16x16x32_bf16(fkm, fw, aa, 0, 0, 0);
        }
#pragma unroll
        for (int r = 0; r < 4; r++) {
          int row = mi * 16 + (lane >> 4) * 4 + r;
          int col = ni * 16 + (lane & 15);
          BcTF[cb + row * 64 + col] = ab[r];
          AcF[cb + row * 64 + col] = aa[r];
        }
      }
  } else {
#pragma unroll
    for (int mi = 0; mi < 4; mi++)
#pragma unroll
      for (int ni = 0; ni < 4; ni++) {
        f32x4 ao = {0.f, 0.f, 0.f, 0.f};
        f32x4 ac = {0.f, 0.f, 0.f, 0.f};
#pragma unroll
        for (int ks = 0; ks < 2; ks++) {
          int aoff = (mi * 16 + (lane & 15)) * 72 + ks * 32 + (lane >> 4) * 8;
          int boff = (ni * 16 + (lane & 15)) * 72 + ks * 32 + (lane >> 4) * 8;
          bf16x8 fc = *(const bf16x8*)&C_b[aoff];
          bf16x8 fu = *(const bf16x8*)&U0T[boff];
          bf16x8 fw = *(const bf16x8*)&WT[boff];
          ao = __builtin_amdgcn_mfma_f32_16x16x32_bf16(fc, fu, ao, 0, 0, 0);
          ac = __builtin_amdgcn_mfma_f32_16x16x32_bf16(fc, fw, ac, 0, 0, 0);
        }
#pragma unroll
        for (int r = 0; r < 4; r++) {
          int t = mi * 16 + (lane >> 4) * 4 + r;
          int col = ni * 16 + (lane & 15);
          O1[(size_t)bh * 65536 + (size_t)(t0 + t) * 64 + col] =
              ao[r] + awS[t] * vS[t * 64 + col];
          QeffF[cb + t * 64 + col] = expf(pvS[t]) * (float)q_b[t * 72 + col] - ac[r];
        }
      }
  }
}

// ---------------------------------------------------------------------------
// K8b: serial state carry, software-pipelined global prefetch.
// ---------------------------------------------------------------------------
__global__ __launch_bounds__(256) void k_scanB(
    const float* __restrict__ AcF, const float* __restrict__ BcTF,
    const float* __restrict__ gcF, float* __restrict__ S0TF) {
  const int bh = blockIdx.x;
  const int tid = threadIdx.x;
  const int w = tid >> 6, lane = tid & 63;
  const int er = tid >> 2, seg = (tid & 3) * 16;
  __shared__ float STf[64 * 68];
  __shared__ __bf16 Sh[64 * 72], Sl[64 * 72], Ac_b[64 * 72];
#pragma unroll
  for (int i = 0; i < 4; i++)
    *(float4*)&STf[er * 68 + seg + i * 4] = make_float4(0.f, 0.f, 0.f, 0.f);
  __syncthreads();

  size_t cbase = (size_t)bh * 16 * 4096;
  float4 acR[4];
  float bctR[16];
#pragma unroll
  for (int i = 0; i < 4; i++)
    acR[i] = *(const float4*)&AcF[cbase + er * 64 + seg + i * 4];
#pragma unroll
  for (int r = 0; r < 4; r++)
#pragma unroll
    for (int ni = 0; ni < 4; ni++) {
      int e = w * 16 + (lane >> 4) * 4 + r;
      int d = ni * 16 + (lane & 15);
      bctR[r * 4 + ni] = BcTF[cbase + e * 64 + d];
    }

  for (int c = 0; c < 16; c++) {
    size_t cb = cbase + (size_t)c * 4096;
#pragma unroll
    for (int i = 0; i < 4; i++) {
      float4 s = *(const float4*)&STf[er * 68 + seg + i * 4];
      *(float4*)&S0TF[cb + er * 64 + seg + i * 4] = s;
      union { __bf16 h[4]; unsigned long long u; } ph, pl, pa;
      float sv[4] = {s.x, s.y, s.z, s.w};
      float av[4] = {acR[i].x, acR[i].y, acR[i].z, acR[i].w};
#pragma unroll
      for (int q = 0; q < 4; q++) {
        __bf16 hv = (__bf16)sv[q];
        ph.h[q] = hv;
        pl.h[q] = (__bf16)(sv[q] - (float)hv);
        pa.h[q] = (__bf16)av[q];
      }
      *(unsigned long long*)&Sh[er * 72 + seg + i * 4] = ph.u;
      *(unsigned long long*)&Sl[er * 72 + seg + i * 4] = pl.u;
      *(unsigned long long*)&Ac_b[er * 72 + seg + i * 4] = pa.u;
    }
    float gC = gcF[bh * 16 + c];
    __syncthreads();

    float4 acN[4];
    float bctN[16];
    if (c < 15) {
      size_t nb = cb + 4096;
#pragma unroll
      for (int i = 0; i < 4; i++)
        acN[i] = *(const float4*)&AcF[nb + er * 64 + seg + i * 4];
#pragma unroll
      for (int r = 0; r < 4; r++)
#pragma unroll
        for (int ni = 0; ni < 4; ni++) {
          int e = w * 16 + (lane >> 4) * 4 + r;
          int d = ni * 16 + (lane & 15);
          bctN[r * 4 + ni] = BcTF[nb + e * 64 + d];
        }
    } else {
#pragma unroll
      for (int i = 0; i < 4; i++) acN[i] = acR[i];
#pragma unroll
      for (int j = 0; j < 16; j++) bctN[j] = bctR[j];
    }

    f32x4 acc[4];
#pragma unroll
    for (int ni = 0; ni < 4; ni++) {
      acc[ni] = (f32x4){0.f, 0.f, 0.f, 0.f};
#pragma unroll
      for (int ks = 0; ks < 2; ks++) {
        int aoff = (w * 16 + (lane & 15)) * 72 + ks * 32 + (lane >> 4) * 8;
        int boff = (ni * 16 + (lane & 15)) * 72 + ks * 32 + (lane >> 4) * 8;
        bf16x8 ah = *(const bf16x8*)&Sh[aoff];
        bf16x8 al = *(const bf16x8*)&Sl[aoff];
        bf16x8 bb = *(const bf16x8*)&Ac_b[boff];
        acc[ni] = __builtin_amdgcn_mfma_f32_16x16x32_bf16(ah, bb, acc[ni], 0, 0, 0);
        acc[ni] = __builtin_amdgcn_mfma_f32_16x16x32_bf16(al, bb, acc[ni], 0, 0, 0);
      }
    }
#pragma unroll
    for (int ni = 0; ni < 4; ni++)
#pragma unroll
      for (int r = 0; r < 4; r++) {
        int e = w * 16 + (lane >> 4) * 4 + r;
        int d = ni * 16 + (lane & 15);
        STf[e * 68 + d] = gC * STf[e * 68 + d] - acc[ni][r] + bctR[r * 4 + ni];
      }
    __syncthreads();
#pragma unroll
    for (int i = 0; i < 4; i++) acR[i] = acN[i];
#pragma unroll
    for (int j = 0; j < 16; j++) bctR[j] = bctN[j];
  }
}

// ---------------------------------------------------------------------------
// K8c+K9 fused: O = O1 + Qeff@S0, then RMS-norm + silu gate -> robuf fp32.
// ---------------------------------------------------------------------------
__global__ __launch_bounds__(256) void k_scanCn(
    const float* __restrict__ S0TF, const float* __restrict__ QeffF,
    const float* __restrict__ obuf, const float* __restrict__ g,
    const float* __restrict__ onw, float* __restrict__ robuf) {
  const int bid = blockIdx.x;
  const int bh = bid >> 4, c = bid & 15, t0c = c * 64;
  const int b = bh >> 4, h = bh & 15;
  const int tid = threadIdx.x;
  const int w = tid >> 6, lane = tid & 63;
  const int er = tid >> 2, seg = (tid & 3) * 16;
  size_t cb = (size_t)bid * 4096;
  __shared__ __bf16 Sh[64 * 72], Sl[64 * 72], Qb[64 * 72];
#pragma unroll
  for (int i = 0; i < 4; i++) {
    float4 s = *(const float4*)&S0TF[cb + er * 64 + seg + i * 4];
    union { __bf16 h[4]; unsigned long long u; } ph, pl;
    float sv[4] = {s.x, s.y, s.z, s.w};
#pragma unroll
    for (int q = 0; q < 4; q++) {
      __bf16 hv = (__bf16)sv[q];
      ph.h[q] = hv;
      pl.h[q] = (__bf16)(sv[q] - (float)hv);
    }
    *(unsigned long long*)&Sh[er * 72 + seg + i * 4] = ph.u;
    *(unsigned long long*)&Sl[er * 72 + seg + i * 4] = pl.u;
    float4 qq = *(const float4*)&QeffF[cb + er * 64 + seg + i * 4];
    union { __bf16 h[4]; unsigned long long u; } pq;
    pq.h[0] = (__bf16)qq.x; pq.h[1] = (__bf16)qq.y;
    pq.h[2] = (__bf16)qq.z; pq.h[3] = (__bf16)qq.w;
    *(unsigned long long*)&Qb[er * 72 + seg + i * 4] = pq.u;
  }
  __syncthreads();
  f32x4 acc[4];
#pragma unroll
  for (int ni = 0; ni < 4; ni++) {
    acc[ni] = (f32x4){0.f, 0.f, 0.f, 0.f};
#pragma unroll
    for (int ks = 0; ks < 2; ks++) {
      int aoff = (w * 16 + (lane & 15)) * 72 + ks * 32 + (lane >> 4) * 8;
      int boff = (ni * 16 + (lane & 15)) * 72 + ks * 32 + (lane >> 4) * 8;
      bf16x8 fq = *(const bf16x8*)&Qb[aoff];
      bf16x8 sh = *(const bf16x8*)&Sh[boff];
      bf16x8 sl = *(const bf16x8*)&Sl[boff];
      acc[ni] = __builtin_amdgcn_mfma_f32_16x16x32_bf16(fq, sh, acc[ni], 0, 0, 0);
      acc[ni] = __builtin_amdgcn_mfma_f32_16x16x32_bf16(fq, sl, acc[ni], 0, 0, 0);
    }
  }
  float onwv[4];
#pragma unroll
  for (int ni = 0; ni < 4; ni++) onwv[ni] = onw[ni * 16 + (lane & 15)];
#pragma unroll
  for (int r = 0; r < 4; r++) {
    int t = w * 16 + (lane >> 4) * 4 + r;
    float o[4];
#pragma unroll
    for (int ni = 0; ni < 4; ni++) {
      int e = ni * 16 + (lane & 15);
      o[ni] = obuf[(size_t)bh * 65536 + (size_t)(t0c + t) * 64 + e] + acc[ni][r];
    }
    float ss = o[0] * o[0] + o[1] * o[1] + o[2] * o[2] + o[3] * o[3];
    ss += __shfl_xor(ss, 1);
    ss += __shfl_xor(ss, 2);
    ss += __shfl_xor(ss, 4);
    ss += __shfl_xor(ss, 8);
    float rinv = rsqrtf(ss * (1.f / 64.f) + 1e-6f);
    size_t gbase = ((size_t)(b * 1024 + t0c + t)) * 1024 + h * 64;
#pragma unroll
    for (int ni = 0; ni < 4; ni++) {
      int e = ni * 16 + (lane & 15);
      float on = o[ni] * rinv * onwv[ni];
      float sil = on / (1.f + expf(-on));
      robuf[gbase + e] = g[gbase + e] * sil;
    }
  }
}

// ---------------------------------------------------------------------------
extern "C" void kernel_launch(void* const* d_in, const int* in_sizes, int n_in,
                              void* d_out, int out_size, void* d_ws, size_t ws_size,
                              hipStream_t stream) {
  (void)in_sizes; (void)n_in; (void)out_size; (void)ws_size;
  const float* x    = (const float*)d_in[0];
  const float* Wq   = (const float*)d_in[1];
  const float* Wk   = (const float*)d_in[2];
  const float* Wv   = (const float*)d_in[3];
  const float* Wg   = (const float*)d_in[4];
  const float* Wo   = (const float*)d_in[5];
  const float* bw   = (const float*)d_in[6];
  const float* bb   = (const float*)d_in[7];
  const float* gkw  = (const float*)d_in[8];
  const float* gkb  = (const float*)d_in[9];
  const float* qcw  = (const float*)d_in[10];
  const float* qcb  = (const float*)d_in[11];
  const float* kcw  = (const float*)d_in[12];
  const float* kcb  = (const float*)d_in[13];
  const float* vcw  = (const float*)d_in[14];
  const float* vcb  = (const float*)d_in[15];
  const float* A_log= (const float*)d_in[16];
  const float* Dp   = (const float*)d_in[17];
  const float* dtb  = (const float*)d_in[18];
  const float* onw  = (const float*)d_in[19];

  char* ws = (char*)d_ws;
  const size_t MB = 1024 * 1024;
  __bf16* Wq_h = (__bf16*)(ws + 8 * MB);
  __bf16* Wq_l = (__bf16*)(ws + 10 * MB);   // unused (q 1-term), region reserved
  __bf16* Wk_h = (__bf16*)(ws + 12 * MB);
  __bf16* Wk_l = (__bf16*)(ws + 14 * MB);
  __bf16* Wv_h = (__bf16*)(ws + 16 * MB);
  __bf16* Wv_l = (__bf16*)(ws + 18 * MB);
  __bf16* Wg_h = (__bf16*)(ws + 20 * MB);
  __bf16* Wg_l = (__bf16*)(ws + 22 * MB);   // unused (g 1-term), region reserved
  __bf16* Wo_h = (__bf16*)(ws + 24 * MB);
  __bf16* Wo_l = (__bf16*)(ws + 26 * MB);   // unused (final 2-term), region reserved
  float* q_pre = (float*)(ws + 28 * MB);
  float* k_pre = (float*)(ws + 36 * MB);
  float* v_pre = (float*)(ws + 44 * MB);
  float* g_buf = (float*)(ws + 52 * MB);
  float* qrb   = (float*)(ws + 0);
  float* krb   = (float*)(ws + 8 * MB);
  float* vr    = (float*)(ws + 16 * MB);
  float* obuf  = v_pre;
  float* AcF   = (float*)(ws + 28 * MB);
  float* BcTF  = (float*)(ws + 36 * MB);
  float* S0TF  = (float*)(ws + 0);
  float* QeffF = (float*)(ws + 16 * MB);
  float* robuf = (float*)(ws + 8 * MB);
  float4* aux  = (float4*)(ws + 60 * MB + 256 * 1024);
  float* gcF   = (float*)(ws + 60 * MB + 768 * 1024);
  float* out   = (float*)d_out;

  k_transp_split<<<dim3(16, 16, 5), 256, 0, stream>>>(
      Wq, Wk, Wv, Wg, Wo,
      Wq_h, Wk_h, Wv_h, Wg_h, Wo_h,
      Wk_l, Wv_l);
  // projections: q 1-term, k 3-term, v 3-term, g 1-term
  k_gemm3f<<<dim3(8, 16, 4), 256, 0, stream>>>(
      x,
      Wq_h, Wk_h, Wv_h, Wg_h,
      Wq_l, Wk_l, Wv_l, Wg_l,
      q_pre, k_pre, v_pre, g_buf,
      1, 3, 3, 1,
      1024, 1024);
  // fused gates + conv + rope + norm + aux
  k_cra<<<8192, 256, 0, stream>>>(q_pre, k_pre, v_pre, x,
                                  qcw, qcb, kcw, kcb, vcw, vcb,
                                  bw, bb, gkw, gkb, A_log, dtb, Dp,
                                  qrb, krb, vr, aux);
  k_scanA<<<512, 128, 0, stream>>>(qrb, krb, vr, aux, obuf, AcF, BcTF, QeffF, gcF);
  k_scanB<<<32, 256, 0, stream>>>(AcF, BcTF, gcF, S0TF);
  k_scanCn<<<512, 256, 0, stream>>>(S0TF, QeffF, obuf, g_buf, onw, robuf);
  // final projection: 2-term (A full precision, Wo-hi)
  k_gemm3f<<<dim3(8, 16, 1), 256, 0, stream>>>(
      robuf,
      Wo_h, Wo_h, Wo_h, Wo_h,
      Wo_l, Wo_l, Wo_l, Wo_l,
      out, out, out, out,
      2, 2, 2, 2,
      1024, 1024);
}

// Round 8
// 335.704 us; speedup vs baseline: 1.2518x; 1.2518x over previous
//
#include <hip/hip_runtime.h>
#include <hip/hip_bf16.h>
#include <cstdint>

// Problem constants
#define T_LEN 1024
#define HIDN  1024
#define NH    16
#define DHD   64

typedef __bf16 bf16x8 __attribute__((ext_vector_type(8)));
typedef float  f32x4  __attribute__((ext_vector_type(4)));

__device__ inline void split8(float4 x0, float4 x1, uint4& hi, uint4& lo) {
  union { __bf16 h[8]; uint4 u; } ph, pl;
  float v[8] = {x0.x, x0.y, x0.z, x0.w, x1.x, x1.y, x1.z, x1.w};
#pragma unroll
  for (int j = 0; j < 8; j++) {
    __bf16 h = (__bf16)v[j];
    ph.h[j] = h;
    pl.h[j] = (__bf16)(v[j] - (float)h);
  }
  hi = ph.u; lo = pl.u;
}

// ---------------------------------------------------------------------------
// K2: transpose 1024x1024 f32 W[k][n] -> bf16 hi/lo Wt[n][k] (5 weights via z)
// ---------------------------------------------------------------------------
__global__ __launch_bounds__(256) void k_transp_split(
    const float* __restrict__ W0, const float* __restrict__ W1,
    const float* __restrict__ W2, const float* __restrict__ W3,
    const float* __restrict__ W4,
    __bf16* __restrict__ H0, __bf16* __restrict__ H1, __bf16* __restrict__ H2,
    __bf16* __restrict__ H3, __bf16* __restrict__ H4,
    __bf16* __restrict__ L0, __bf16* __restrict__ L1, __bf16* __restrict__ L2,
    __bf16* __restrict__ L3, __bf16* __restrict__ L4) {
  const float* W; __bf16* Th; __bf16* Tl;
  switch (blockIdx.z) {
    case 0: W = W0; Th = H0; Tl = L0; break;
    case 1: W = W1; Th = H1; Tl = L1; break;
    case 2: W = W2; Th = H2; Tl = L2; break;
    case 3: W = W3; Th = H3; Tl = L3; break;
    default: W = W4; Th = H4; Tl = L4; break;
  }
  __shared__ float tile[64][65];
  int tid = threadIdx.x;
  int r0 = tid >> 4;          // 0..15
  int c0 = (tid & 15) * 4;    // 0..60
  int kbase = blockIdx.y * 64, nbase = blockIdx.x * 64;
#pragma unroll
  for (int rr = 0; rr < 4; rr++) {
    int r = r0 + rr * 16;
    float4 v = *(const float4*)(W + (size_t)(kbase + r) * 1024 + nbase + c0);
    tile[r][c0 + 0] = v.x; tile[r][c0 + 1] = v.y;
    tile[r][c0 + 2] = v.z; tile[r][c0 + 3] = v.w;
  }
  __syncthreads();
#pragma unroll
  for (int rr = 0; rr < 4; rr++) {
    int n = r0 + rr * 16;
    union { __bf16 h[4]; unsigned long long u; } ph, pl;
#pragma unroll
    for (int j = 0; j < 4; j++) {
      float v = tile[c0 + j][n];
      __bf16 h = (__bf16)v;
      ph.h[j] = h;
      pl.h[j] = (__bf16)(v - (float)h);
    }
    *(unsigned long long*)(Th + (size_t)(nbase + n) * 1024 + kbase + c0) = ph.u;
    *(unsigned long long*)(Tl + (size_t)(nbase + n) * 1024 + kbase + c0) = pl.u;
  }
}

// ---------------------------------------------------------------------------
// K3: split-precision GEMM, A fp32 (inline hi/lo split), B pre-split bf16.
// C = Ah*Bh + Al*Bh + Ah*Bl. 128x128 tile, BK=32, 4 waves.
// ---------------------------------------------------------------------------
#define LDT 40
__global__ __launch_bounds__(256) void k_gemm3f(
    const float* __restrict__ Af,
    const __bf16* __restrict__ Bh0, const __bf16* __restrict__ Bh1,
    const __bf16* __restrict__ Bh2, const __bf16* __restrict__ Bh3,
    const __bf16* __restrict__ Bl0, const __bf16* __restrict__ Bl1,
    const __bf16* __restrict__ Bl2, const __bf16* __restrict__ Bl3,
    float* __restrict__ C0, float* __restrict__ C1,
    float* __restrict__ C2, float* __restrict__ C3,
    int Kdim, int Ncols) {
  const __bf16* Bh; const __bf16* Bl; float* C;
  switch (blockIdx.z) {
    case 0: Bh = Bh0; Bl = Bl0; C = C0; break;
    case 1: Bh = Bh1; Bl = Bl1; C = C1; break;
    case 2: Bh = Bh2; Bl = Bl2; C = C2; break;
    default: Bh = Bh3; Bl = Bl3; C = C3; break;
  }
  __shared__ __bf16 Ash[128 * LDT];
  __shared__ __bf16 Asl[128 * LDT];
  __shared__ __bf16 Bsh[128 * LDT];
  __shared__ __bf16 Bsl[128 * LDT];
  const int tid = threadIdx.x;
  const int lane = tid & 63;
  const int wave = tid >> 6;
  const int wr = wave >> 1, wc = wave & 1;
  const int rowA0 = blockIdx.y * 128;
  const int colB0 = blockIdx.x * 128;
  const int sseg = tid & 3;
  const int srow0 = tid >> 2;
  const int srow1 = srow0 + 64;

  f32x4 acc[4][4] = {};

  for (int k0 = 0; k0 < Kdim; k0 += 32) {
    size_t a0 = (size_t)(rowA0 + srow0) * Kdim + k0 + sseg * 8;
    size_t a1 = (size_t)(rowA0 + srow1) * Kdim + k0 + sseg * 8;
    size_t b0 = (size_t)(colB0 + srow0) * Kdim + k0 + sseg * 8;
    size_t b1 = (size_t)(colB0 + srow1) * Kdim + k0 + sseg * 8;
    float4 a00 = *(const float4*)(Af + a0);
    float4 a01 = *(const float4*)(Af + a0 + 4);
    float4 a10 = *(const float4*)(Af + a1);
    float4 a11 = *(const float4*)(Af + a1 + 4);
    uint4 rbh0 = *(const uint4*)(Bh + b0);
    uint4 rbh1 = *(const uint4*)(Bh + b1);
    uint4 rbl0 = *(const uint4*)(Bl + b0);
    uint4 rbl1 = *(const uint4*)(Bl + b1);
    uint4 rah0, ral0, rah1, ral1;
    split8(a00, a01, rah0, ral0);
    split8(a10, a11, rah1, ral1);
    __syncthreads();
    *(uint4*)&Ash[srow0 * LDT + sseg * 8] = rah0;
    *(uint4*)&Ash[srow1 * LDT + sseg * 8] = rah1;
    *(uint4*)&Asl[srow0 * LDT + sseg * 8] = ral0;
    *(uint4*)&Asl[srow1 * LDT + sseg * 8] = ral1;
    *(uint4*)&Bsh[srow0 * LDT + sseg * 8] = rbh0;
    *(uint4*)&Bsh[srow1 * LDT + sseg * 8] = rbh1;
    *(uint4*)&Bsl[srow0 * LDT + sseg * 8] = rbl0;
    *(uint4*)&Bsl[srow1 * LDT + sseg * 8] = rbl1;
    __syncthreads();
    bf16x8 afh[4], afl[4], bfh[4], bfl[4];
#pragma unroll
    for (int mi = 0; mi < 4; mi++) {
      int off = (wr * 64 + mi * 16 + (lane & 15)) * LDT + (lane >> 4) * 8;
      afh[mi] = *(const bf16x8*)&Ash[off];
      afl[mi] = *(const bf16x8*)&Asl[off];
    }
#pragma unroll
    for (int ni = 0; ni < 4; ni++) {
      int off = (wc * 64 + ni * 16 + (lane & 15)) * LDT + (lane >> 4) * 8;
      bfh[ni] = *(const bf16x8*)&Bsh[off];
      bfl[ni] = *(const bf16x8*)&Bsl[off];
    }
#pragma unroll
    for (int mi = 0; mi < 4; mi++)
#pragma unroll
      for (int ni = 0; ni < 4; ni++) {
        acc[mi][ni] = __builtin_amdgcn_mfma_f32_16x16x32_bf16(afh[mi], bfh[ni], acc[mi][ni], 0, 0, 0);
        acc[mi][ni] = __builtin_amdgcn_mfma_f32_16x16x32_bf16(afl[mi], bfh[ni], acc[mi][ni], 0, 0, 0);
        acc[mi][ni] = __builtin_amdgcn_mfma_f32_16x16x32_bf16(afh[mi], bfl[ni], acc[mi][ni], 0, 0, 0);
      }
  }
#pragma unroll
  for (int mi = 0; mi < 4; mi++)
#pragma unroll
    for (int ni = 0; ni < 4; ni++) {
      int col = colB0 + wc * 64 + ni * 16 + (lane & 15);
#pragma unroll
      for (int r = 0; r < 4; r++) {
        int row = rowA0 + wr * 64 + mi * 16 + (lane >> 4) * 4 + r;
        C[(size_t)row * Ncols + col] = acc[mi][ni][r];
      }
    }
}

// ---------------------------------------------------------------------------
// K4: gates (standalone — tid layout keeps bw/gkw reads coalesced:
// consecutive tids = consecutive h -> consecutive addresses)
// ---------------------------------------------------------------------------
__global__ __launch_bounds__(256) void k_gates(
    const float* __restrict__ x, const float* __restrict__ bw,
    const float* __restrict__ bb, const float* __restrict__ gkw,
    const float* __restrict__ gkb, const float* __restrict__ A_log,
    const float* __restrict__ dt_bias,
    float* __restrict__ alphaB, float* __restrict__ betaB) {
  const int bt = blockIdx.x;
  const int tid = threadIdx.x;
  const int h = tid & 15;
  const int chunk = tid >> 4;
  const float* xr = x + (size_t)bt * HIDN;
  float d1 = 0.f, d2 = 0.f;
#pragma unroll 8
  for (int j = 0; j < 64; j++) {
    int k = chunk * 64 + j;
    float xv = xr[k];
    d1 += xv * bw[k * 16 + h];
    d2 += xv * gkw[k * 16 + h];
  }
  __shared__ float p1[16][16], p2[16][16];
  p1[chunk][h] = d1; p2[chunk][h] = d2;
  __syncthreads();
  if (tid < 16) {
    float s1 = 0.f, s2 = 0.f;
#pragma unroll
    for (int c = 0; c < 16; c++) { s1 += p1[c][tid]; s2 += p2[c][tid]; }
    float beta = 1.f / (1.f + expf(-(s1 + bb[tid])));
    float z = s2 + gkb[tid] + dt_bias[tid];
    float sp = fmaxf(z, 0.f) + log1pf(expf(-fabsf(z)));
    float alpha = expf(-expf(A_log[tid]) * sp);
    alphaB[(size_t)bt * 16 + tid] = alpha;
    betaB[(size_t)bt * 16 + tid] = beta;
  }
}

// ---------------------------------------------------------------------------
// K_CRA: fused causal dwconv(K=4)+SiLU -> RoPE -> L2 norm -> aux pack.
// One wave per (bt,h); lane = channel-within-head d.
// ---------------------------------------------------------------------------
__global__ __launch_bounds__(256) void k_cra(
    const float* __restrict__ qp, const float* __restrict__ kp,
    const float* __restrict__ vp,
    const float* __restrict__ qcw, const float* __restrict__ qcb,
    const float* __restrict__ kcw, const float* __restrict__ kcb,
    const float* __restrict__ vcw, const float* __restrict__ vcb,
    const float* __restrict__ alphaB, const float* __restrict__ betaB,
    const float* __restrict__ Dp,
    float* __restrict__ qr, float* __restrict__ kr, float* __restrict__ vr,
    float4* __restrict__ aux) {
  int widx = blockIdx.x * 4 + (threadIdx.x >> 6);
  int lane = threadIdx.x & 63;
  int h = widx & 15;
  int bt = widx >> 4;
  int t = bt & 1023, b = bt >> 10;
  int c = h * 64 + lane;
  size_t colbase = ((size_t)b * 1024) * 1024 + c;

  // conv + silu for q, k, v
  float4 wq = *(const float4*)(qcw + (size_t)c * 4);
  float4 wk = *(const float4*)(kcw + (size_t)c * 4);
  float4 wv = *(const float4*)(vcw + (size_t)c * 4);
  float aq = qcb[c], ak = kcb[c], av = vcb[c];
  {
    float x0 = qp[colbase + (size_t)t * 1024];
    float y0 = kp[colbase + (size_t)t * 1024];
    float z0 = vp[colbase + (size_t)t * 1024];
    aq += wq.w * x0; ak += wk.w * y0; av += wv.w * z0;
    if (t >= 1) {
      float x1 = qp[colbase + (size_t)(t - 1) * 1024];
      float y1 = kp[colbase + (size_t)(t - 1) * 1024];
      float z1 = vp[colbase + (size_t)(t - 1) * 1024];
      aq += wq.z * x1; ak += wk.z * y1; av += wv.z * z1;
    }
    if (t >= 2) {
      float x2 = qp[colbase + (size_t)(t - 2) * 1024];
      float y2 = kp[colbase + (size_t)(t - 2) * 1024];
      float z2v = vp[colbase + (size_t)(t - 2) * 1024];
      aq += wq.y * x2; ak += wk.y * y2; av += wv.y * z2v;
    }
    if (t >= 3) {
      float x3 = qp[colbase + (size_t)(t - 3) * 1024];
      float y3 = kp[colbase + (size_t)(t - 3) * 1024];
      float z3 = vp[colbase + (size_t)(t - 3) * 1024];
      aq += wq.x * x3; ak += wk.x * y3; av += wv.x * z3;
    }
  }
  float yq = aq / (1.f + expf(-aq));
  float yk = ak / (1.f + expf(-ak));
  float yv = av / (1.f + expf(-av));

  // rope
  int i = lane & 31;
  float fr = expf(-(float)(2 * (i & 15)) * (9.210340371976184f / 32.f));
  float ang = (float)t * fr;
  float cv = cosf(ang), sv = sinf(ang);
  float q1 = __shfl(yq, 2 * i), q2 = __shfl(yq, 2 * i + 1);
  float k1 = __shfl(yk, 2 * i), k2 = __shfl(yk, 2 * i + 1);
  float qo = (lane < 32) ? (q1 * cv - q2 * sv) : (q1 * sv + q2 * cv);
  float ko = (lane < 32) ? (k1 * cv - k2 * sv) : (k1 * sv + k2 * cv);

  // L2 norm + aux
  float qs = qo * qo, ks2 = ko * ko;
#pragma unroll
  for (int m = 1; m < 64; m <<= 1) { qs += __shfl_xor(qs, m); ks2 += __shfl_xor(ks2, m); }
  float qn = qo * rsqrtf(qs + 1e-6f);
  float kn = ko * rsqrtf(ks2 + 1e-6f);
  float dq = qn * kn;
#pragma unroll
  for (int m = 1; m < 64; m <<= 1) dq += __shfl_xor(dq, m);
  size_t obase = ((size_t)(b * 16 + h) * 1024 + t) * 64;
  qr[obase + lane] = qn;
  kr[obase + lane] = kn;
  vr[obase + lane] = yv;
  if (lane == 0) {
    float alpha = alphaB[(size_t)bt * 16 + h];
    float beta = betaB[(size_t)bt * 16 + h];
    aux[(size_t)(b * 16 + h) * 1024 + t] = make_float4(alpha, beta, alpha * beta, Dp[h] * dq);
  }
}

// ---------------------------------------------------------------------------
// K8a: WY-form scan, S0-independent per-chunk work.
// ---------------------------------------------------------------------------
__global__ __launch_bounds__(128) void k_scanA(
    const float* __restrict__ qr, const float* __restrict__ kr,
    const float* __restrict__ vr, const float4* __restrict__ aux,
    float* __restrict__ O1, float* __restrict__ AcF,
    float* __restrict__ BcTF, float* __restrict__ QeffF,
    float* __restrict__ gcF) {
  const int bid = blockIdx.x;
  const int bh = bid >> 4, c = bid & 15;
  const int t0 = c * 64;
  const int tid = threadIdx.x;
  const int w = tid >> 6, lane = tid & 63;
  const float* qB = qr + (size_t)bh * 65536 + (size_t)t0 * 64;
  const float* kB = kr + (size_t)bh * 65536 + (size_t)t0 * 64;
  const float* vB = vr + (size_t)bh * 65536 + (size_t)t0 * 64;
  const float4* auxB = aux + (size_t)bh * T_LEN + t0;

  __shared__ __bf16 q_b[64 * 72];
  __shared__ __bf16 k_b[64 * 72];
  __shared__ __bf16 kT_b[64 * 72];
  __shared__ __bf16 C_b[64 * 72];
  __shared__ __bf16 U0T[64 * 72];
  __shared__ __bf16 WT[64 * 72];
  __shared__ float  vS[64 * 64];
  __shared__ float  MTf[64 * 68];
  __shared__ float  lgS[64], pvS[64], beS[64], awS[64], enS[64];

  if (w == 0) {
    float4 a4 = auxB[lane];
    float lg = logf(a4.x);
#pragma unroll
    for (int off = 1; off < 64; off <<= 1) {
      float tv = __shfl_up(lg, off);
      if (lane >= off) lg += tv;
    }
    float pv = __shfl_up(lg, 1);
    if (lane == 0) pv = 0.f;
    float lgTot = __shfl(lg, 63);
    lgS[lane] = lg; pvS[lane] = pv; beS[lane] = a4.y; awS[lane] = a4.w;
    enS[lane] = expf(lgTot - lg);
    if (lane == 0) gcF[bid] = expf(lgTot);
  }
#pragma unroll
  for (int p = 0; p < 4; p++) {
    int s = p * 128 + tid;
    int row = s >> 3, col8 = s & 7;
    const float* gq = qB + (size_t)row * 64 + col8 * 8;
    const float* gk = kB + (size_t)row * 64 + col8 * 8;
    const float* gv = vB + (size_t)row * 64 + col8 * 8;
    float4 q0 = *(const float4*)gq, q1 = *(const float4*)(gq + 4);
    float4 k0 = *(const float4*)gk, k1 = *(const float4*)(gk + 4);
    float4 v0 = *(const float4*)gv, v1 = *(const float4*)(gv + 4);
    union { __bf16 h[8]; uint4 u; } pq, pk;
    pq.h[0] = (__bf16)q0.x; pq.h[1] = (__bf16)q0.y; pq.h[2] = (__bf16)q0.z; pq.h[3] = (__bf16)q0.w;
    pq.h[4] = (__bf16)q1.x; pq.h[5] = (__bf16)q1.y; pq.h[6] = (__bf16)q1.z; pq.h[7] = (__bf16)q1.w;
    pk.h[0] = (__bf16)k0.x; pk.h[1] = (__bf16)k0.y; pk.h[2] = (__bf16)k0.z; pk.h[3] = (__bf16)k0.w;
    pk.h[4] = (__bf16)k1.x; pk.h[5] = (__bf16)k1.y; pk.h[6] = (__bf16)k1.z; pk.h[7] = (__bf16)k1.w;
    *(uint4*)&q_b[row * 72 + col8 * 8] = pq.u;
    *(uint4*)&k_b[row * 72 + col8 * 8] = pk.u;
    *(float4*)&vS[row * 64 + col8 * 8] = v0;
    *(float4*)&vS[row * 64 + col8 * 8 + 4] = v1;
  }
  __syncthreads();

#pragma unroll
  for (int mm = 0; mm < 2; mm++) {
    int mi = w * 2 + mm;
#pragma unroll
    for (int ni = 0; ni < 4; ni++) {
      f32x4 akk = {0.f, 0.f, 0.f, 0.f};
      f32x4 aqk = {0.f, 0.f, 0.f, 0.f};
#pragma unroll
      for (int ks = 0; ks < 2; ks++) {
        bf16x8 fa_k = *(const bf16x8*)&k_b[(mi * 16 + (lane & 15)) * 72 + ks * 32 + (lane >> 4) * 8];
        bf16x8 fa_q = *(const bf16x8*)&q_b[(mi * 16 + (lane & 15)) * 72 + ks * 32 + (lane >> 4) * 8];
        bf16x8 fb_k = *(const bf16x8*)&k_b[(ni * 16 + (lane & 15)) * 72 + ks * 32 + (lane >> 4) * 8];
        akk = __builtin_amdgcn_mfma_f32_16x16x32_bf16(fa_k, fb_k, akk, 0, 0, 0);
        aqk = __builtin_amdgcn_mfma_f32_16x16x32_bf16(fa_q, fb_k, aqk, 0, 0, 0);
      }
#pragma unroll
      for (int r = 0; r < 4; r++) {
        int row = mi * 16 + (lane >> 4) * 4 + r;
        int col = ni * 16 + (lane & 15);
        float mt = 0.f, cv = 0.f;
        if (row > col) {
          mt = beS[row] * expf(lgS[row] - lgS[col]) * akk[r];
          cv = expf(pvS[row] - lgS[col]) * aqk[r];
        }
        MTf[col * 68 + row] = mt;
        C_b[row * 72 + col] = (__bf16)cv;
      }
    }
  }
  __syncthreads();

  if (w == 1) {
#pragma unroll
    for (int t8 = 0; t8 < 8; t8++) {
      union { __bf16 h[8]; uint4 u; } pt;
#pragma unroll
      for (int q = 0; q < 8; q++) {
        int t = t8 * 8 + q;
        pt.h[q] = (__bf16)((float)k_b[t * 72 + lane] * enS[t]);
      }
      *(uint4*)&kT_b[lane * 72 + t8 * 8] = pt.u;
    }
  }

  {
    float u[64];
    if (w == 0) {
#pragma unroll
      for (int j = 0; j < 64; j++) u[j] = beS[j] * vS[j * 64 + lane];
    } else {
#pragma unroll
      for (int j = 0; j < 64; j++) u[j] = beS[j] * expf(lgS[j]) * (float)k_b[j * 72 + lane];
    }
    __bf16* dst = (w == 0) ? U0T : WT;
#pragma unroll
    for (int j = 0; j < 64; j++) {
      dst[lane * 72 + j] = (__bf16)u[j];
      float uj = u[j];
#pragma unroll
      for (int g = (j >> 4); g < 4; g++) {
#pragma unroll
        for (int q4 = 0; q4 < 4; q4++) {
          const float4 m4 = *(const float4*)&MTf[j * 68 + g * 16 + q4 * 4];
          u[g * 16 + q4 * 4 + 0] -= m4.x * uj;
          u[g * 16 + q4 * 4 + 1] -= m4.y * uj;
          u[g * 16 + q4 * 4 + 2] -= m4.z * uj;
          u[g * 16 + q4 * 4 + 3] -= m4.w * uj;
        }
      }
    }
  }
  __syncthreads();

  size_t cb = (size_t)bid * 4096;
  if (w == 0) {
#pragma unroll
    for (int mi = 0; mi < 4; mi++)
#pragma unroll
      for (int ni = 0; ni < 4; ni++) {
        f32x4 ab = {0.f, 0.f, 0.f, 0.f};
        f32x4 aa = {0.f, 0.f, 0.f, 0.f};
#pragma unroll
        for (int ks = 0; ks < 2; ks++) {
          int aoff = (mi * 16 + (lane & 15)) * 72 + ks * 32 + (lane >> 4) * 8;
          int boff = (ni * 16 + (lane & 15)) * 72 + ks * 32 + (lane >> 4) * 8;
          bf16x8 fu = *(const bf16x8*)&U0T[aoff];
          bf16x8 fkm = *(const bf16x8*)&kT_b[aoff];
          bf16x8 fkn = *(const bf16x8*)&kT_b[boff];
          bf16x8 fw = *(const bf16x8*)&WT[boff];
          ab = __builtin_amdgcn_mfma_f32_16x16x32_bf16(fu, fkn, ab, 0, 0, 0);
          aa = __builtin_amdgcn_mfma_f32_16x16x32_bf16(fkm, fw, aa, 0, 0, 0);
        }
#pragma unroll
        for (int r = 0; r < 4; r++) {
          int row = mi * 16 + (lane >> 4) * 4 + r;
          int col = ni * 16 + (lane & 15);
          BcTF[cb + row * 64 + col] = ab[r];
          AcF[cb + row * 64 + col] = aa[r];
        }
      }
  } else {
#pragma unroll
    for (int mi = 0; mi < 4; mi++)
#pragma unroll
      for (int ni = 0; ni < 4; ni++) {
        f32x4 ao = {0.f, 0.f, 0.f, 0.f};
        f32x4 ac = {0.f, 0.f, 0.f, 0.f};
#pragma unroll
        for (int ks = 0; ks < 2; ks++) {
          int aoff = (mi * 16 + (lane & 15)) * 72 + ks * 32 + (lane >> 4) * 8;
          int boff = (ni * 16 + (lane & 15)) * 72 + ks * 32 + (lane >> 4) * 8;
          bf16x8 fc = *(const bf16x8*)&C_b[aoff];
          bf16x8 fu = *(const bf16x8*)&U0T[boff];
          bf16x8 fw = *(const bf16x8*)&WT[boff];
          ao = __builtin_amdgcn_mfma_f32_16x16x32_bf16(fc, fu, ao, 0, 0, 0);
          ac = __builtin_amdgcn_mfma_f32_16x16x32_bf16(fc, fw, ac, 0, 0, 0);
        }
#pragma unroll
        for (int r = 0; r < 4; r++) {
          int t = mi * 16 + (lane >> 4) * 4 + r;
          int col = ni * 16 + (lane & 15);
          O1[(size_t)bh * 65536 + (size_t)(t0 + t) * 64 + col] =
              ao[r] + awS[t] * vS[t * 64 + col];
          QeffF[cb + t * 64 + col] = expf(pvS[t]) * (float)q_b[t * 72 + col] - ac[r];
        }
      }
  }
}

// ---------------------------------------------------------------------------
// K8b: serial state carry, software-pipelined global prefetch.
// ---------------------------------------------------------------------------
__global__ __launch_bounds__(256) void k_scanB(
    const float* __restrict__ AcF, const float* __restrict__ BcTF,
    const float* __restrict__ gcF, float* __restrict__ S0TF) {
  const int bh = blockIdx.x;
  const int tid = threadIdx.x;
  const int w = tid >> 6, lane = tid & 63;
  const int er = tid >> 2, seg = (tid & 3) * 16;
  __shared__ float STf[64 * 68];
  __shared__ __bf16 Sh[64 * 72], Sl[64 * 72], Ac_b[64 * 72];
#pragma unroll
  for (int i = 0; i < 4; i++)
    *(float4*)&STf[er * 68 + seg + i * 4] = make_float4(0.f, 0.f, 0.f, 0.f);
  __syncthreads();

  size_t cbase = (size_t)bh * 16 * 4096;
  float4 acR[4];
  float bctR[16];
#pragma unroll
  for (int i = 0; i < 4; i++)
    acR[i] = *(const float4*)&AcF[cbase + er * 64 + seg + i * 4];
#pragma unroll
  for (int r = 0; r < 4; r++)
#pragma unroll
    for (int ni = 0; ni < 4; ni++) {
      int e = w * 16 + (lane >> 4) * 4 + r;
      int d = ni * 16 + (lane & 15);
      bctR[r * 4 + ni] = BcTF[cbase + e * 64 + d];
    }

  for (int c = 0; c < 16; c++) {
    size_t cb = cbase + (size_t)c * 4096;
#pragma unroll
    for (int i = 0; i < 4; i++) {
      float4 s = *(const float4*)&STf[er * 68 + seg + i * 4];
      *(float4*)&S0TF[cb + er * 64 + seg + i * 4] = s;
      union { __bf16 h[4]; unsigned long long u; } ph, pl, pa;
      float sv[4] = {s.x, s.y, s.z, s.w};
      float av[4] = {acR[i].x, acR[i].y, acR[i].z, acR[i].w};
#pragma unroll
      for (int q = 0; q < 4; q++) {
        __bf16 hv = (__bf16)sv[q];
        ph.h[q] = hv;
        pl.h[q] = (__bf16)(sv[q] - (float)hv);
        pa.h[q] = (__bf16)av[q];
      }
      *(unsigned long long*)&Sh[er * 72 + seg + i * 4] = ph.u;
      *(unsigned long long*)&Sl[er * 72 + seg + i * 4] = pl.u;
      *(unsigned long long*)&Ac_b[er * 72 + seg + i * 4] = pa.u;
    }
    float gC = gcF[bh * 16 + c];
    __syncthreads();

    float4 acN[4];
    float bctN[16];
    if (c < 15) {
      size_t nb = cb + 4096;
#pragma unroll
      for (int i = 0; i < 4; i++)
        acN[i] = *(const float4*)&AcF[nb + er * 64 + seg + i * 4];
#pragma unroll
      for (int r = 0; r < 4; r++)
#pragma unroll
        for (int ni = 0; ni < 4; ni++) {
          int e = w * 16 + (lane >> 4) * 4 + r;
          int d = ni * 16 + (lane & 15);
          bctN[r * 4 + ni] = BcTF[nb + e * 64 + d];
        }
    } else {
#pragma unroll
      for (int i = 0; i < 4; i++) acN[i] = acR[i];
#pragma unroll
      for (int j = 0; j < 16; j++) bctN[j] = bctR[j];
    }

    f32x4 acc[4];
#pragma unroll
    for (int ni = 0; ni < 4; ni++) {
      acc[ni] = (f32x4){0.f, 0.f, 0.f, 0.f};
#pragma unroll
      for (int ks = 0; ks < 2; ks++) {
        int aoff = (w * 16 + (lane & 15)) * 72 + ks * 32 + (lane >> 4) * 8;
        int boff = (ni * 16 + (lane & 15)) * 72 + ks * 32 + (lane >> 4) * 8;
        bf16x8 ah = *(const bf16x8*)&Sh[aoff];
        bf16x8 al = *(const bf16x8*)&Sl[aoff];
        bf16x8 bb = *(const bf16x8*)&Ac_b[boff];
        acc[ni] = __builtin_amdgcn_mfma_f32_16x16x32_bf16(ah, bb, acc[ni], 0, 0, 0);
        acc[ni] = __builtin_amdgcn_mfma_f32_16x16x32_bf16(al, bb, acc[ni], 0, 0, 0);
      }
    }
#pragma unroll
    for (int ni = 0; ni < 4; ni++)
#pragma unroll
      for (int r = 0; r < 4; r++) {
        int e = w * 16 + (lane >> 4) * 4 + r;
        int d = ni * 16 + (lane & 15);
        STf[e * 68 + d] = gC * STf[e * 68 + d] - acc[ni][r] + bctR[r * 4 + ni];
      }
    __syncthreads();
#pragma unroll
    for (int i = 0; i < 4; i++) acR[i] = acN[i];
#pragma unroll
    for (int j = 0; j < 16; j++) bctR[j] = bctN[j];
  }
}

// ---------------------------------------------------------------------------
// K8c+K9 fused: O = O1 + Qeff@S0, then RMS-norm + silu gate -> robuf fp32.
// ---------------------------------------------------------------------------
__global__ __launch_bounds__(256) void k_scanCn(
    const float* __restrict__ S0TF, const float* __restrict__ QeffF,
    const float* __restrict__ obuf, const float* __restrict__ g,
    const float* __restrict__ onw, float* __restrict__ robuf) {
  const int bid = blockIdx.x;
  const int bh = bid >> 4, c = bid & 15, t0c = c * 64;
  const int b = bh >> 4, h = bh & 15;
  const int tid = threadIdx.x;
  const int w = tid >> 6, lane = tid & 63;
  const int er = tid >> 2, seg = (tid & 3) * 16;
  size_t cb = (size_t)bid * 4096;
  __shared__ __bf16 Sh[64 * 72], Sl[64 * 72], Qb[64 * 72];
#pragma unroll
  for (int i = 0; i < 4; i++) {
    float4 s = *(const float4*)&S0TF[cb + er * 64 + seg + i * 4];
    union { __bf16 h[4]; unsigned long long u; } ph, pl;
    float sv[4] = {s.x, s.y, s.z, s.w};
#pragma unroll
    for (int q = 0; q < 4; q++) {
      __bf16 hv = (__bf16)sv[q];
      ph.h[q] = hv;
      pl.h[q] = (__bf16)(sv[q] - (float)hv);
    }
    *(unsigned long long*)&Sh[er * 72 + seg + i * 4] = ph.u;
    *(unsigned long long*)&Sl[er * 72 + seg + i * 4] = pl.u;
    float4 qq = *(const float4*)&QeffF[cb + er * 64 + seg + i * 4];
    union { __bf16 h[4]; unsigned long long u; } pq;
    pq.h[0] = (__bf16)qq.x; pq.h[1] = (__bf16)qq.y;
    pq.h[2] = (__bf16)qq.z; pq.h[3] = (__bf16)qq.w;
    *(unsigned long long*)&Qb[er * 72 + seg + i * 4] = pq.u;
  }
  __syncthreads();
  f32x4 acc[4];
#pragma unroll
  for (int ni = 0; ni < 4; ni++) {
    acc[ni] = (f32x4){0.f, 0.f, 0.f, 0.f};
#pragma unroll
    for (int ks = 0; ks < 2; ks++) {
      int aoff = (w * 16 + (lane & 15)) * 72 + ks * 32 + (lane >> 4) * 8;
      int boff = (ni * 16 + (lane & 15)) * 72 + ks * 32 + (lane >> 4) * 8;
      bf16x8 fq = *(const bf16x8*)&Qb[aoff];
      bf16x8 sh = *(const bf16x8*)&Sh[boff];
      bf16x8 sl = *(const bf16x8*)&Sl[boff];
      acc[ni] = __builtin_amdgcn_mfma_f32_16x16x32_bf16(fq, sh, acc[ni], 0, 0, 0);
      acc[ni] = __builtin_amdgcn_mfma_f32_16x16x32_bf16(fq, sl, acc[ni], 0, 0, 0);
    }
  }
  float onwv[4];
#pragma unroll
  for (int ni = 0; ni < 4; ni++) onwv[ni] = onw[ni * 16 + (lane & 15)];
#pragma unroll
  for (int r = 0; r < 4; r++) {
    int t = w * 16 + (lane >> 4) * 4 + r;
    float o[4];
#pragma unroll
    for (int ni = 0; ni < 4; ni++) {
      int e = ni * 16 + (lane & 15);
      o[ni] = obuf[(size_t)bh * 65536 + (size_t)(t0c + t) * 64 + e] + acc[ni][r];
    }
    float ss = o[0] * o[0] + o[1] * o[1] + o[2] * o[2] + o[3] * o[3];
    ss += __shfl_xor(ss, 1);
    ss += __shfl_xor(ss, 2);
    ss += __shfl_xor(ss, 4);
    ss += __shfl_xor(ss, 8);
    float rinv = rsqrtf(ss * (1.f / 64.f) + 1e-6f);
    size_t gbase = ((size_t)(b * 1024 + t0c + t)) * 1024 + h * 64;
#pragma unroll
    for (int ni = 0; ni < 4; ni++) {
      int e = ni * 16 + (lane & 15);
      float on = o[ni] * rinv * onwv[ni];
      float sil = on / (1.f + expf(-on));
      robuf[gbase + e] = g[gbase + e] * sil;
    }
  }
}

// ---------------------------------------------------------------------------
extern "C" void kernel_launch(void* const* d_in, const int* in_sizes, int n_in,
                              void* d_out, int out_size, void* d_ws, size_t ws_size,
                              hipStream_t stream) {
  (void)in_sizes; (void)n_in; (void)out_size; (void)ws_size;
  const float* x    = (const float*)d_in[0];
  const float* Wq   = (const float*)d_in[1];
  const float* Wk   = (const float*)d_in[2];
  const float* Wv   = (const float*)d_in[3];
  const float* Wg   = (const float*)d_in[4];
  const float* Wo   = (const float*)d_in[5];
  const float* bw   = (const float*)d_in[6];
  const float* bb   = (const float*)d_in[7];
  const float* gkw  = (const float*)d_in[8];
  const float* gkb  = (const float*)d_in[9];
  const float* qcw  = (const float*)d_in[10];
  const float* qcb  = (const float*)d_in[11];
  const float* kcw  = (const float*)d_in[12];
  const float* kcb  = (const float*)d_in[13];
  const float* vcw  = (const float*)d_in[14];
  const float* vcb  = (const float*)d_in[15];
  const float* A_log= (const float*)d_in[16];
  const float* Dp   = (const float*)d_in[17];
  const float* dtb  = (const float*)d_in[18];
  const float* onw  = (const float*)d_in[19];

  char* ws = (char*)d_ws;
  const size_t MB = 1024 * 1024;
  __bf16* Wq_h = (__bf16*)(ws + 8 * MB);
  __bf16* Wq_l = (__bf16*)(ws + 10 * MB);
  __bf16* Wk_h = (__bf16*)(ws + 12 * MB);
  __bf16* Wk_l = (__bf16*)(ws + 14 * MB);
  __bf16* Wv_h = (__bf16*)(ws + 16 * MB);
  __bf16* Wv_l = (__bf16*)(ws + 18 * MB);
  __bf16* Wg_h = (__bf16*)(ws + 20 * MB);
  __bf16* Wg_l = (__bf16*)(ws + 22 * MB);
  __bf16* Wo_h = (__bf16*)(ws + 24 * MB);
  __bf16* Wo_l = (__bf16*)(ws + 26 * MB);
  float* q_pre = (float*)(ws + 28 * MB);
  float* k_pre = (float*)(ws + 36 * MB);
  float* v_pre = (float*)(ws + 44 * MB);
  float* g_buf = (float*)(ws + 52 * MB);
  float* qrb   = (float*)(ws + 0);
  float* krb   = (float*)(ws + 8 * MB);
  float* vr    = (float*)(ws + 16 * MB);
  float* obuf  = v_pre;
  float* AcF   = (float*)(ws + 28 * MB);
  float* BcTF  = (float*)(ws + 36 * MB);
  float* S0TF  = (float*)(ws + 0);
  float* QeffF = (float*)(ws + 16 * MB);
  float* robuf = (float*)(ws + 8 * MB);
  float* alphaB = (float*)(ws + 60 * MB);
  float* betaB  = (float*)(ws + 60 * MB + 128 * 1024);
  float4* aux   = (float4*)(ws + 60 * MB + 256 * 1024);
  float* gcF    = (float*)(ws + 60 * MB + 768 * 1024);
  float* out    = (float*)d_out;

  k_transp_split<<<dim3(16, 16, 5), 256, 0, stream>>>(
      Wq, Wk, Wv, Wg, Wo,
      Wq_h, Wk_h, Wv_h, Wg_h, Wo_h,
      Wq_l, Wk_l, Wv_l, Wg_l, Wo_l);
  k_gates<<<2048, 256, 0, stream>>>(x, bw, bb, gkw, gkb, A_log, dtb, alphaB, betaB);
  k_gemm3f<<<dim3(8, 16, 4), 256, 0, stream>>>(
      x,
      Wq_h, Wk_h, Wv_h, Wg_h,
      Wq_l, Wk_l, Wv_l, Wg_l,
      q_pre, k_pre, v_pre, g_buf, 1024, 1024);
  k_cra<<<8192, 256, 0, stream>>>(q_pre, k_pre, v_pre,
                                  qcw, qcb, kcw, kcb, vcw, vcb,
                                  alphaB, betaB, Dp, qrb, krb, vr, aux);
  k_scanA<<<512, 128, 0, stream>>>(qrb, krb, vr, aux, obuf, AcF, BcTF, QeffF, gcF);
  k_scanB<<<32, 256, 0, stream>>>(AcF, BcTF, gcF, S0TF);
  k_scanCn<<<512, 256, 0, stream>>>(S0TF, QeffF, obuf, g_buf, onw, robuf);
  k_gemm3f<<<dim3(8, 16, 1), 256, 0, stream>>>(
      robuf,
      Wo_h, Wo_h, Wo_h, Wo_h,
      Wo_l, Wo_l, Wo_l, Wo_l,
      out, out, out, out, 1024, 1024);
}

// Round 10
// 320.910 us; speedup vs baseline: 1.3095x; 1.0461x over previous
//
#include <hip/hip_runtime.h>
#include <hip/hip_bf16.h>
#include <cstdint>

// Problem constants
#define T_LEN 1024
#define HIDN  1024
#define NH    16
#define DHD   64

typedef __bf16 bf16x8 __attribute__((ext_vector_type(8)));
typedef float  f32x4  __attribute__((ext_vector_type(4)));

__device__ inline void split8(float4 x0, float4 x1, uint4& hi, uint4& lo) {
  union { __bf16 h[8]; uint4 u; } ph, pl;
  float v[8] = {x0.x, x0.y, x0.z, x0.w, x1.x, x1.y, x1.z, x1.w};
#pragma unroll
  for (int j = 0; j < 8; j++) {
    __bf16 h = (__bf16)v[j];
    ph.h[j] = h;
    pl.h[j] = (__bf16)(v[j] - (float)h);
  }
  hi = ph.u; lo = pl.u;
}

// ---------------------------------------------------------------------------
// K2: transpose 1024x1024 f32 W[k][n] -> bf16 hi/lo Wt[n][k] (5 weights via z)
// ---------------------------------------------------------------------------
__global__ __launch_bounds__(256) void k_transp_split(
    const float* __restrict__ W0, const float* __restrict__ W1,
    const float* __restrict__ W2, const float* __restrict__ W3,
    const float* __restrict__ W4,
    __bf16* __restrict__ H0, __bf16* __restrict__ H1, __bf16* __restrict__ H2,
    __bf16* __restrict__ H3, __bf16* __restrict__ H4,
    __bf16* __restrict__ L0, __bf16* __restrict__ L1, __bf16* __restrict__ L2,
    __bf16* __restrict__ L3, __bf16* __restrict__ L4) {
  const float* W; __bf16* Th; __bf16* Tl;
  switch (blockIdx.z) {
    case 0: W = W0; Th = H0; Tl = L0; break;
    case 1: W = W1; Th = H1; Tl = L1; break;
    case 2: W = W2; Th = H2; Tl = L2; break;
    case 3: W = W3; Th = H3; Tl = L3; break;
    default: W = W4; Th = H4; Tl = L4; break;
  }
  __shared__ float tile[64][65];
  int tid = threadIdx.x;
  int r0 = tid >> 4;          // 0..15
  int c0 = (tid & 15) * 4;    // 0..60
  int kbase = blockIdx.y * 64, nbase = blockIdx.x * 64;
#pragma unroll
  for (int rr = 0; rr < 4; rr++) {
    int r = r0 + rr * 16;
    float4 v = *(const float4*)(W + (size_t)(kbase + r) * 1024 + nbase + c0);
    tile[r][c0 + 0] = v.x; tile[r][c0 + 1] = v.y;
    tile[r][c0 + 2] = v.z; tile[r][c0 + 3] = v.w;
  }
  __syncthreads();
#pragma unroll
  for (int rr = 0; rr < 4; rr++) {
    int n = r0 + rr * 16;
    union { __bf16 h[4]; unsigned long long u; } ph, pl;
#pragma unroll
    for (int j = 0; j < 4; j++) {
      float v = tile[c0 + j][n];
      __bf16 h = (__bf16)v;
      ph.h[j] = h;
      pl.h[j] = (__bf16)(v - (float)h);
    }
    *(unsigned long long*)(Th + (size_t)(nbase + n) * 1024 + kbase + c0) = ph.u;
    *(unsigned long long*)(Tl + (size_t)(nbase + n) * 1024 + kbase + c0) = pl.u;
  }
}

// ---------------------------------------------------------------------------
// K3: split-precision GEMM, A fp32 (inline hi/lo split), B pre-split bf16.
// C = Ah*Bh + Al*Bh + Ah*Bl. 128x128 tile, BK=32, 4 waves.
// ---------------------------------------------------------------------------
#define LDT 40
__global__ __launch_bounds__(256) void k_gemm3f(
    const float* __restrict__ Af,
    const __bf16* __restrict__ Bh0, const __bf16* __restrict__ Bh1,
    const __bf16* __restrict__ Bh2, const __bf16* __restrict__ Bh3,
    const __bf16* __restrict__ Bl0, const __bf16* __restrict__ Bl1,
    const __bf16* __restrict__ Bl2, const __bf16* __restrict__ Bl3,
    float* __restrict__ C0, float* __restrict__ C1,
    float* __restrict__ C2, float* __restrict__ C3,
    int Kdim, int Ncols) {
  const __bf16* Bh; const __bf16* Bl; float* C;
  switch (blockIdx.z) {
    case 0: Bh = Bh0; Bl = Bl0; C = C0; break;
    case 1: Bh = Bh1; Bl = Bl1; C = C1; break;
    case 2: Bh = Bh2; Bl = Bl2; C = C2; break;
    default: Bh = Bh3; Bl = Bl3; C = C3; break;
  }
  __shared__ __bf16 Ash[128 * LDT];
  __shared__ __bf16 Asl[128 * LDT];
  __shared__ __bf16 Bsh[128 * LDT];
  __shared__ __bf16 Bsl[128 * LDT];
  const int tid = threadIdx.x;
  const int lane = tid & 63;
  const int wave = tid >> 6;
  const int wr = wave >> 1, wc = wave & 1;
  const int rowA0 = blockIdx.y * 128;
  const int colB0 = blockIdx.x * 128;
  const int sseg = tid & 3;
  const int srow0 = tid >> 2;
  const int srow1 = srow0 + 64;

  f32x4 acc[4][4] = {};

  for (int k0 = 0; k0 < Kdim; k0 += 32) {
    size_t a0 = (size_t)(rowA0 + srow0) * Kdim + k0 + sseg * 8;
    size_t a1 = (size_t)(rowA0 + srow1) * Kdim + k0 + sseg * 8;
    size_t b0 = (size_t)(colB0 + srow0) * Kdim + k0 + sseg * 8;
    size_t b1 = (size_t)(colB0 + srow1) * Kdim + k0 + sseg * 8;
    float4 a00 = *(const float4*)(Af + a0);
    float4 a01 = *(const float4*)(Af + a0 + 4);
    float4 a10 = *(const float4*)(Af + a1);
    float4 a11 = *(const float4*)(Af + a1 + 4);
    uint4 rbh0 = *(const uint4*)(Bh + b0);
    uint4 rbh1 = *(const uint4*)(Bh + b1);
    uint4 rbl0 = *(const uint4*)(Bl + b0);
    uint4 rbl1 = *(const uint4*)(Bl + b1);
    uint4 rah0, ral0, rah1, ral1;
    split8(a00, a01, rah0, ral0);
    split8(a10, a11, rah1, ral1);
    __syncthreads();
    *(uint4*)&Ash[srow0 * LDT + sseg * 8] = rah0;
    *(uint4*)&Ash[srow1 * LDT + sseg * 8] = rah1;
    *(uint4*)&Asl[srow0 * LDT + sseg * 8] = ral0;
    *(uint4*)&Asl[srow1 * LDT + sseg * 8] = ral1;
    *(uint4*)&Bsh[srow0 * LDT + sseg * 8] = rbh0;
    *(uint4*)&Bsh[srow1 * LDT + sseg * 8] = rbh1;
    *(uint4*)&Bsl[srow0 * LDT + sseg * 8] = rbl0;
    *(uint4*)&Bsl[srow1 * LDT + sseg * 8] = rbl1;
    __syncthreads();
    bf16x8 afh[4], afl[4], bfh[4], bfl[4];
#pragma unroll
    for (int mi = 0; mi < 4; mi++) {
      int off = (wr * 64 + mi * 16 + (lane & 15)) * LDT + (lane >> 4) * 8;
      afh[mi] = *(const bf16x8*)&Ash[off];
      afl[mi] = *(const bf16x8*)&Asl[off];
    }
#pragma unroll
    for (int ni = 0; ni < 4; ni++) {
      int off = (wc * 64 + ni * 16 + (lane & 15)) * LDT + (lane >> 4) * 8;
      bfh[ni] = *(const bf16x8*)&Bsh[off];
      bfl[ni] = *(const bf16x8*)&Bsl[off];
    }
#pragma unroll
    for (int mi = 0; mi < 4; mi++)
#pragma unroll
      for (int ni = 0; ni < 4; ni++) {
        acc[mi][ni] = __builtin_amdgcn_mfma_f32_16x16x32_bf16(afh[mi], bfh[ni], acc[mi][ni], 0, 0, 0);
        acc[mi][ni] = __builtin_amdgcn_mfma_f32_16x16x32_bf16(afl[mi], bfh[ni], acc[mi][ni], 0, 0, 0);
        acc[mi][ni] = __builtin_amdgcn_mfma_f32_16x16x32_bf16(afh[mi], bfl[ni], acc[mi][ni], 0, 0, 0);
      }
  }
#pragma unroll
  for (int mi = 0; mi < 4; mi++)
#pragma unroll
    for (int ni = 0; ni < 4; ni++) {
      int col = colB0 + wc * 64 + ni * 16 + (lane & 15);
#pragma unroll
      for (int r = 0; r < 4; r++) {
        int row = rowA0 + wr * 64 + mi * 16 + (lane >> 4) * 4 + r;
        C[(size_t)row * Ncols + col] = acc[mi][ni][r];
      }
    }
}

// ---------------------------------------------------------------------------
// K4: gates (standalone; coalesced weight reads)
// ---------------------------------------------------------------------------
__global__ __launch_bounds__(256) void k_gates(
    const float* __restrict__ x, const float* __restrict__ bw,
    const float* __restrict__ bb, const float* __restrict__ gkw,
    const float* __restrict__ gkb, const float* __restrict__ A_log,
    const float* __restrict__ dt_bias,
    float* __restrict__ alphaB, float* __restrict__ betaB) {
  const int bt = blockIdx.x;
  const int tid = threadIdx.x;
  const int h = tid & 15;
  const int chunk = tid >> 4;
  const float* xr = x + (size_t)bt * HIDN;
  float d1 = 0.f, d2 = 0.f;
#pragma unroll 8
  for (int j = 0; j < 64; j++) {
    int k = chunk * 64 + j;
    float xv = xr[k];
    d1 += xv * bw[k * 16 + h];
    d2 += xv * gkw[k * 16 + h];
  }
  __shared__ float p1[16][16], p2[16][16];
  p1[chunk][h] = d1; p2[chunk][h] = d2;
  __syncthreads();
  if (tid < 16) {
    float s1 = 0.f, s2 = 0.f;
#pragma unroll
    for (int c = 0; c < 16; c++) { s1 += p1[c][tid]; s2 += p2[c][tid]; }
    float beta = 1.f / (1.f + expf(-(s1 + bb[tid])));
    float z = s2 + gkb[tid] + dt_bias[tid];
    float sp = fmaxf(z, 0.f) + log1pf(expf(-fabsf(z)));
    float alpha = expf(-expf(A_log[tid]) * sp);
    alphaB[(size_t)bt * 16 + tid] = alpha;
    betaB[(size_t)bt * 16 + tid] = beta;
  }
}

// ---------------------------------------------------------------------------
// K_CRA: fused causal dwconv(K=4)+SiLU -> RoPE -> L2 norm -> aux pack.
// ---------------------------------------------------------------------------
__global__ __launch_bounds__(256) void k_cra(
    const float* __restrict__ qp, const float* __restrict__ kp,
    const float* __restrict__ vp,
    const float* __restrict__ qcw, const float* __restrict__ qcb,
    const float* __restrict__ kcw, const float* __restrict__ kcb,
    const float* __restrict__ vcw, const float* __restrict__ vcb,
    const float* __restrict__ alphaB, const float* __restrict__ betaB,
    const float* __restrict__ Dp,
    float* __restrict__ qr, float* __restrict__ kr, float* __restrict__ vr,
    float4* __restrict__ aux) {
  int widx = blockIdx.x * 4 + (threadIdx.x >> 6);
  int lane = threadIdx.x & 63;
  int h = widx & 15;
  int bt = widx >> 4;
  int t = bt & 1023, b = bt >> 10;
  int c = h * 64 + lane;
  size_t colbase = ((size_t)b * 1024) * 1024 + c;

  float4 wq = *(const float4*)(qcw + (size_t)c * 4);
  float4 wk = *(const float4*)(kcw + (size_t)c * 4);
  float4 wv = *(const float4*)(vcw + (size_t)c * 4);
  float aq = qcb[c], ak = kcb[c], av = vcb[c];
  {
    float x0 = qp[colbase + (size_t)t * 1024];
    float y0 = kp[colbase + (size_t)t * 1024];
    float z0 = vp[colbase + (size_t)t * 1024];
    aq += wq.w * x0; ak += wk.w * y0; av += wv.w * z0;
    if (t >= 1) {
      float x1 = qp[colbase + (size_t)(t - 1) * 1024];
      float y1 = kp[colbase + (size_t)(t - 1) * 1024];
      float z1 = vp[colbase + (size_t)(t - 1) * 1024];
      aq += wq.z * x1; ak += wk.z * y1; av += wv.z * z1;
    }
    if (t >= 2) {
      float x2 = qp[colbase + (size_t)(t - 2) * 1024];
      float y2 = kp[colbase + (size_t)(t - 2) * 1024];
      float z2v = vp[colbase + (size_t)(t - 2) * 1024];
      aq += wq.y * x2; ak += wk.y * y2; av += wv.y * z2v;
    }
    if (t >= 3) {
      float x3 = qp[colbase + (size_t)(t - 3) * 1024];
      float y3 = kp[colbase + (size_t)(t - 3) * 1024];
      float z3 = vp[colbase + (size_t)(t - 3) * 1024];
      aq += wq.x * x3; ak += wk.x * y3; av += wv.x * z3;
    }
  }
  float yq = aq / (1.f + expf(-aq));
  float yk = ak / (1.f + expf(-ak));
  float yv = av / (1.f + expf(-av));

  int i = lane & 31;
  float fr = expf(-(float)(2 * (i & 15)) * (9.210340371976184f / 32.f));
  float ang = (float)t * fr;
  float cv = cosf(ang), sv = sinf(ang);
  float q1 = __shfl(yq, 2 * i), q2 = __shfl(yq, 2 * i + 1);
  float k1 = __shfl(yk, 2 * i), k2 = __shfl(yk, 2 * i + 1);
  float qo = (lane < 32) ? (q1 * cv - q2 * sv) : (q1 * sv + q2 * cv);
  float ko = (lane < 32) ? (k1 * cv - k2 * sv) : (k1 * sv + k2 * cv);

  float qs = qo * qo, ks2 = ko * ko;
#pragma unroll
  for (int m = 1; m < 64; m <<= 1) { qs += __shfl_xor(qs, m); ks2 += __shfl_xor(ks2, m); }
  float qn = qo * rsqrtf(qs + 1e-6f);
  float kn = ko * rsqrtf(ks2 + 1e-6f);
  float dq = qn * kn;
#pragma unroll
  for (int m = 1; m < 64; m <<= 1) dq += __shfl_xor(dq, m);
  size_t obase = ((size_t)(b * 16 + h) * 1024 + t) * 64;
  qr[obase + lane] = qn;
  kr[obase + lane] = kn;
  vr[obase + lane] = yv;
  if (lane == 0) {
    float alpha = alphaB[(size_t)bt * 16 + h];
    float beta = betaB[(size_t)bt * 16 + h];
    aux[(size_t)(b * 16 + h) * 1024 + t] = make_float4(alpha, beta, alpha * beta, Dp[h] * dq);
  }
}

// ---------------------------------------------------------------------------
// K8a: WY-form scan, S0-independent per-chunk work. NOW 4 waves (256 thr):
//  phase2 MFMA split mi=w; kT-build on wave2 overlapping solves (w0,w1);
//  phase5 split across all 4 waves.
// ---------------------------------------------------------------------------
__global__ __launch_bounds__(256) void k_scanA(
    const float* __restrict__ qr, const float* __restrict__ kr,
    const float* __restrict__ vr, const float4* __restrict__ aux,
    float* __restrict__ O1, float* __restrict__ AcF,
    float* __restrict__ BcTF, float* __restrict__ QeffF,
    float* __restrict__ gcF) {
  const int bid = blockIdx.x;
  const int bh = bid >> 4, c = bid & 15;
  const int t0 = c * 64;
  const int tid = threadIdx.x;
  const int w = tid >> 6, lane = tid & 63;
  const float* qB = qr + (size_t)bh * 65536 + (size_t)t0 * 64;
  const float* kB = kr + (size_t)bh * 65536 + (size_t)t0 * 64;
  const float* vB = vr + (size_t)bh * 65536 + (size_t)t0 * 64;
  const float4* auxB = aux + (size_t)bh * T_LEN + t0;

  __shared__ __bf16 q_b[64 * 72];
  __shared__ __bf16 k_b[64 * 72];
  __shared__ __bf16 kT_b[64 * 72];
  __shared__ __bf16 C_b[64 * 72];
  __shared__ __bf16 U0T[64 * 72];
  __shared__ __bf16 WT[64 * 72];
  __shared__ float  vS[64 * 64];
  __shared__ float  MTf[64 * 68];
  __shared__ float  lgS[64], pvS[64], beS[64], awS[64], enS[64];

  // ---- phase 1: aux + prefix decay (wave 0), global loads (all waves) ----
  if (w == 0) {
    float4 a4 = auxB[lane];
    float lg = logf(a4.x);
#pragma unroll
    for (int off = 1; off < 64; off <<= 1) {
      float tv = __shfl_up(lg, off);
      if (lane >= off) lg += tv;
    }
    float pv = __shfl_up(lg, 1);
    if (lane == 0) pv = 0.f;
    float lgTot = __shfl(lg, 63);
    lgS[lane] = lg; pvS[lane] = pv; beS[lane] = a4.y; awS[lane] = a4.w;
    enS[lane] = expf(lgTot - lg);
    if (lane == 0) gcF[bid] = expf(lgTot);
  }
#pragma unroll
  for (int p = 0; p < 2; p++) {
    int s = p * 256 + tid;
    int row = s >> 3, col8 = s & 7;
    const float* gq = qB + (size_t)row * 64 + col8 * 8;
    const float* gk = kB + (size_t)row * 64 + col8 * 8;
    const float* gv = vB + (size_t)row * 64 + col8 * 8;
    float4 q0 = *(const float4*)gq, q1 = *(const float4*)(gq + 4);
    float4 k0 = *(const float4*)gk, k1 = *(const float4*)(gk + 4);
    float4 v0 = *(const float4*)gv, v1 = *(const float4*)(gv + 4);
    union { __bf16 h[8]; uint4 u; } pq, pk;
    pq.h[0] = (__bf16)q0.x; pq.h[1] = (__bf16)q0.y; pq.h[2] = (__bf16)q0.z; pq.h[3] = (__bf16)q0.w;
    pq.h[4] = (__bf16)q1.x; pq.h[5] = (__bf16)q1.y; pq.h[6] = (__bf16)q1.z; pq.h[7] = (__bf16)q1.w;
    pk.h[0] = (__bf16)k0.x; pk.h[1] = (__bf16)k0.y; pk.h[2] = (__bf16)k0.z; pk.h[3] = (__bf16)k0.w;
    pk.h[4] = (__bf16)k1.x; pk.h[5] = (__bf16)k1.y; pk.h[6] = (__bf16)k1.z; pk.h[7] = (__bf16)k1.w;
    *(uint4*)&q_b[row * 72 + col8 * 8] = pq.u;
    *(uint4*)&k_b[row * 72 + col8 * 8] = pk.u;
    *(float4*)&vS[row * 64 + col8 * 8] = v0;
    *(float4*)&vS[row * 64 + col8 * 8 + 4] = v1;
  }
  __syncthreads();

  // ---- phase 2: KK->MT and QK->C, mi = w (one row-band per wave) ----
  {
    const int mi = w;
#pragma unroll
    for (int ni = 0; ni < 4; ni++) {
      f32x4 akk = {0.f, 0.f, 0.f, 0.f};
      f32x4 aqk = {0.f, 0.f, 0.f, 0.f};
#pragma unroll
      for (int ks = 0; ks < 2; ks++) {
        bf16x8 fa_k = *(const bf16x8*)&k_b[(mi * 16 + (lane & 15)) * 72 + ks * 32 + (lane >> 4) * 8];
        bf16x8 fa_q = *(const bf16x8*)&q_b[(mi * 16 + (lane & 15)) * 72 + ks * 32 + (lane >> 4) * 8];
        bf16x8 fb_k = *(const bf16x8*)&k_b[(ni * 16 + (lane & 15)) * 72 + ks * 32 + (lane >> 4) * 8];
        akk = __builtin_amdgcn_mfma_f32_16x16x32_bf16(fa_k, fb_k, akk, 0, 0, 0);
        aqk = __builtin_amdgcn_mfma_f32_16x16x32_bf16(fa_q, fb_k, aqk, 0, 0, 0);
      }
#pragma unroll
      for (int r = 0; r < 4; r++) {
        int row = mi * 16 + (lane >> 4) * 4 + r;
        int col = ni * 16 + (lane & 15);
        float mt = 0.f, cv = 0.f;
        if (row > col) {
          mt = beS[row] * expf(lgS[row] - lgS[col]) * akk[r];
          cv = expf(pvS[row] - lgS[col]) * aqk[r];
        }
        MTf[col * 68 + row] = mt;
        C_b[row * 72 + col] = (__bf16)cv;
      }
    }
  }
  __syncthreads();

  // ---- phase 3+4: wave2 builds scaled K^T; waves 0,1 run the two solves ----
  if (w == 2) {
#pragma unroll
    for (int t8 = 0; t8 < 8; t8++) {
      union { __bf16 h[8]; uint4 u; } pt;
#pragma unroll
      for (int q = 0; q < 8; q++) {
        int t = t8 * 8 + q;
        pt.h[q] = (__bf16)((float)k_b[t * 72 + lane] * enS[t]);
      }
      *(uint4*)&kT_b[lane * 72 + t8 * 8] = pt.u;
    }
  }
  if (w < 2) {
    float u[64];
    if (w == 0) {
#pragma unroll
      for (int j = 0; j < 64; j++) u[j] = beS[j] * vS[j * 64 + lane];
    } else {
#pragma unroll
      for (int j = 0; j < 64; j++) u[j] = beS[j] * expf(lgS[j]) * (float)k_b[j * 72 + lane];
    }
    __bf16* dst = (w == 0) ? U0T : WT;
#pragma unroll
    for (int j = 0; j < 64; j++) {
      dst[lane * 72 + j] = (__bf16)u[j];
      float uj = u[j];
#pragma unroll
      for (int g = (j >> 4); g < 4; g++) {
#pragma unroll
        for (int q4 = 0; q4 < 4; q4++) {
          const float4 m4 = *(const float4*)&MTf[j * 68 + g * 16 + q4 * 4];
          u[g * 16 + q4 * 4 + 0] -= m4.x * uj;
          u[g * 16 + q4 * 4 + 1] -= m4.y * uj;
          u[g * 16 + q4 * 4 + 2] -= m4.z * uj;
          u[g * 16 + q4 * 4 + 3] -= m4.w * uj;
        }
      }
    }
  }
  __syncthreads();

  // ---- phase 5: output products, split across 4 waves ----
  size_t cb = (size_t)bid * 4096;
  const int mi0 = (w >> 1) * 2;
  if ((w & 1) == 0) {
    // w0: mi 0,1 ; w2: mi 2,3  -> BcT, Ac
#pragma unroll
    for (int mm = 0; mm < 2; mm++) {
      int mi = mi0 + mm;
#pragma unroll
      for (int ni = 0; ni < 4; ni++) {
        f32x4 ab = {0.f, 0.f, 0.f, 0.f};
        f32x4 aa = {0.f, 0.f, 0.f, 0.f};
#pragma unroll
        for (int ks = 0; ks < 2; ks++) {
          int aoff = (mi * 16 + (lane & 15)) * 72 + ks * 32 + (lane >> 4) * 8;
          int boff = (ni * 16 + (lane & 15)) * 72 + ks * 32 + (lane >> 4) * 8;
          bf16x8 fu = *(const bf16x8*)&U0T[aoff];
          bf16x8 fkm = *(const bf16x8*)&kT_b[aoff];
          bf16x8 fkn = *(const bf16x8*)&kT_b[boff];
          bf16x8 fw = *(const bf16x8*)&WT[boff];
          ab = __builtin_amdgcn_mfma_f32_16x16x32_bf16(fu, fkn, ab, 0, 0, 0);
          aa = __builtin_amdgcn_mfma_f32_16x16x32_bf16(fkm, fw, aa, 0, 0, 0);
        }
#pragma unroll
        for (int r = 0; r < 4; r++) {
          int row = mi * 16 + (lane >> 4) * 4 + r;
          int col = ni * 16 + (lane & 15);
          BcTF[cb + row * 64 + col] = ab[r];
          AcF[cb + row * 64 + col] = aa[r];
        }
      }
    }
  } else {
    // w1: mi 0,1 ; w3: mi 2,3  -> O1, Qeff
#pragma unroll
    for (int mm = 0; mm < 2; mm++) {
      int mi = mi0 + mm;
#pragma unroll
      for (int ni = 0; ni < 4; ni++) {
        f32x4 ao = {0.f, 0.f, 0.f, 0.f};
        f32x4 ac = {0.f, 0.f, 0.f, 0.f};
#pragma unroll
        for (int ks = 0; ks < 2; ks++) {
          int aoff = (mi * 16 + (lane & 15)) * 72 + ks * 32 + (lane >> 4) * 8;
          int boff = (ni * 16 + (lane & 15)) * 72 + ks * 32 + (lane >> 4) * 8;
          bf16x8 fc = *(const bf16x8*)&C_b[aoff];
          bf16x8 fu = *(const bf16x8*)&U0T[boff];
          bf16x8 fw = *(const bf16x8*)&WT[boff];
          ao = __builtin_amdgcn_mfma_f32_16x16x32_bf16(fc, fu, ao, 0, 0, 0);
          ac = __builtin_amdgcn_mfma_f32_16x16x32_bf16(fc, fw, ac, 0, 0, 0);
        }
#pragma unroll
        for (int r = 0; r < 4; r++) {
          int t = mi * 16 + (lane >> 4) * 4 + r;
          int col = ni * 16 + (lane & 15);
          O1[(size_t)bh * 65536 + (size_t)(t0 + t) * 64 + col] =
              ao[r] + awS[t] * vS[t * 64 + col];
          QeffF[cb + t * 64 + col] = expf(pvS[t]) * (float)q_b[t * 72 + col] - ac[r];
        }
      }
    }
  }
}

// ---------------------------------------------------------------------------
// K8b: serial state carry, row-parallel: grid 128 = (bh, e-group of 16 rows).
// Each block evolves 16 independent rows of S^T through the 16 chunks:
//   S^T_part <- gC*S^T_part - S^T_part Ac^T + BcT_part
// MFMA on M=16 tiles (1 wave per 16-col output block). Register prefetch of
// next chunk's Ac/BcT overlaps the MFMA.
// ---------------------------------------------------------------------------
__global__ __launch_bounds__(256) void k_scanB(
    const float* __restrict__ AcF, const float* __restrict__ BcTF,
    const float* __restrict__ gcF, float* __restrict__ S0TF) {
  const int bid = blockIdx.x;           // bh*4 + eg
  const int bh = bid >> 2, eg = bid & 3;
  const int e0 = eg * 16;
  const int tid = threadIdx.x;
  const int w = tid >> 6, lane = tid & 63;
  const int er = tid >> 2, seg = (tid & 3) * 16;     // Ac staging (64 rows x 64)
  const int er2 = tid >> 4, seg2 = (tid & 15) * 4;   // S-part staging (16 x 64)
  __shared__ float STf[16 * 68];
  __shared__ __bf16 Sh[16 * 72], Sl[16 * 72], Ac_b[64 * 72];
  *(float4*)&STf[er2 * 68 + seg2] = make_float4(0.f, 0.f, 0.f, 0.f);
  __syncthreads();

  size_t cbase = (size_t)bh * 16 * 4096;
  // prologue: prefetch chunk 0
  float4 acR[4];
  float bctR[4];
#pragma unroll
  for (int i = 0; i < 4; i++)
    acR[i] = *(const float4*)&AcF[cbase + er * 64 + seg + i * 4];
#pragma unroll
  for (int r = 0; r < 4; r++)
    bctR[r] = BcTF[cbase + (size_t)(e0 + (lane >> 4) * 4 + r) * 64 + w * 16 + (lane & 15)];

  for (int c = 0; c < 16; c++) {
    size_t cb = cbase + (size_t)c * 4096;
    // stage S-part -> Sh/Sl, emit S0T rows e0..e0+15
    {
      float4 s = *(const float4*)&STf[er2 * 68 + seg2];
      *(float4*)&S0TF[cb + (size_t)(e0 + er2) * 64 + seg2] = s;
      union { __bf16 h[4]; unsigned long long u; } ph, pl;
      float sv[4] = {s.x, s.y, s.z, s.w};
#pragma unroll
      for (int q = 0; q < 4; q++) {
        __bf16 hv = (__bf16)sv[q];
        ph.h[q] = hv;
        pl.h[q] = (__bf16)(sv[q] - (float)hv);
      }
      *(unsigned long long*)&Sh[er2 * 72 + seg2] = ph.u;
      *(unsigned long long*)&Sl[er2 * 72 + seg2] = pl.u;
    }
    // stage Ac regs -> LDS bf16
#pragma unroll
    for (int i = 0; i < 4; i++) {
      union { __bf16 h[4]; unsigned long long u; } pa;
      pa.h[0] = (__bf16)acR[i].x; pa.h[1] = (__bf16)acR[i].y;
      pa.h[2] = (__bf16)acR[i].z; pa.h[3] = (__bf16)acR[i].w;
      *(unsigned long long*)&Ac_b[er * 72 + seg + i * 4] = pa.u;
    }
    float gC = gcF[bh * 16 + c];
    __syncthreads();

    // prefetch chunk c+1 (stays in flight across the MFMA)
    float4 acN[4];
    float bctN[4];
    if (c < 15) {
      size_t nb = cb + 4096;
#pragma unroll
      for (int i = 0; i < 4; i++)
        acN[i] = *(const float4*)&AcF[nb + er * 64 + seg + i * 4];
#pragma unroll
      for (int r = 0; r < 4; r++)
        bctN[r] = BcTF[nb + (size_t)(e0 + (lane >> 4) * 4 + r) * 64 + w * 16 + (lane & 15)];
    } else {
#pragma unroll
      for (int i = 0; i < 4; i++) acN[i] = acR[i];
#pragma unroll
      for (int r = 0; r < 4; r++) bctN[r] = bctR[r];
    }

    // MFMA: wave w owns output cols d in [w*16, w*16+16)
    f32x4 acc = {0.f, 0.f, 0.f, 0.f};
#pragma unroll
    for (int ks = 0; ks < 2; ks++) {
      int aoff = (lane & 15) * 72 + ks * 32 + (lane >> 4) * 8;
      int boff = (w * 16 + (lane & 15)) * 72 + ks * 32 + (lane >> 4) * 8;
      bf16x8 ah = *(const bf16x8*)&Sh[aoff];
      bf16x8 al = *(const bf16x8*)&Sl[aoff];
      bf16x8 bb = *(const bf16x8*)&Ac_b[boff];
      acc = __builtin_amdgcn_mfma_f32_16x16x32_bf16(ah, bb, acc, 0, 0, 0);
      acc = __builtin_amdgcn_mfma_f32_16x16x32_bf16(al, bb, acc, 0, 0, 0);
    }
#pragma unroll
    for (int r = 0; r < 4; r++) {
      int e = (lane >> 4) * 4 + r;           // local row 0..15
      int d = w * 16 + (lane & 15);
      STf[e * 68 + d] = gC * STf[e * 68 + d] - acc[r] + bctR[r];
    }
    __syncthreads();
#pragma unroll
    for (int i = 0; i < 4; i++) acR[i] = acN[i];
#pragma unroll
    for (int r = 0; r < 4; r++) bctR[r] = bctN[r];
  }
}

// ---------------------------------------------------------------------------
// K8c+K9 fused: O = O1 + Qeff@S0, then RMS-norm + silu gate -> robuf fp32.
// ---------------------------------------------------------------------------
__global__ __launch_bounds__(256) void k_scanCn(
    const float* __restrict__ S0TF, const float* __restrict__ QeffF,
    const float* __restrict__ obuf, const float* __restrict__ g,
    const float* __restrict__ onw, float* __restrict__ robuf) {
  const int bid = blockIdx.x;
  const int bh = bid >> 4, c = bid & 15, t0c = c * 64;
  const int b = bh >> 4, h = bh & 15;
  const int tid = threadIdx.x;
  const int w = tid >> 6, lane = tid & 63;
  const int er = tid >> 2, seg = (tid & 3) * 16;
  size_t cb = (size_t)bid * 4096;
  __shared__ __bf16 Sh[64 * 72], Sl[64 * 72], Qb[64 * 72];
#pragma unroll
  for (int i = 0; i < 4; i++) {
    float4 s = *(const float4*)&S0TF[cb + er * 64 + seg + i * 4];
    union { __bf16 h[4]; unsigned long long u; } ph, pl;
    float sv[4] = {s.x, s.y, s.z, s.w};
#pragma unroll
    for (int q = 0; q < 4; q++) {
      __bf16 hv = (__bf16)sv[q];
      ph.h[q] = hv;
      pl.h[q] = (__bf16)(sv[q] - (float)hv);
    }
    *(unsigned long long*)&Sh[er * 72 + seg + i * 4] = ph.u;
    *(unsigned long long*)&Sl[er * 72 + seg + i * 4] = pl.u;
    float4 qq = *(const float4*)&QeffF[cb + er * 64 + seg + i * 4];
    union { __bf16 h[4]; unsigned long long u; } pq;
    pq.h[0] = (__bf16)qq.x; pq.h[1] = (__bf16)qq.y;
    pq.h[2] = (__bf16)qq.z; pq.h[3] = (__bf16)qq.w;
    *(unsigned long long*)&Qb[er * 72 + seg + i * 4] = pq.u;
  }
  __syncthreads();
  f32x4 acc[4];
#pragma unroll
  for (int ni = 0; ni < 4; ni++) {
    acc[ni] = (f32x4){0.f, 0.f, 0.f, 0.f};
#pragma unroll
    for (int ks = 0; ks < 2; ks++) {
      int aoff = (w * 16 + (lane & 15)) * 72 + ks * 32 + (lane >> 4) * 8;
      int boff = (ni * 16 + (lane & 15)) * 72 + ks * 32 + (lane >> 4) * 8;
      bf16x8 fq = *(const bf16x8*)&Qb[aoff];
      bf16x8 sh = *(const bf16x8*)&Sh[boff];
      bf16x8 sl = *(const bf16x8*)&Sl[boff];
      acc[ni] = __builtin_amdgcn_mfma_f32_16x16x32_bf16(fq, sh, acc[ni], 0, 0, 0);
      acc[ni] = __builtin_amdgcn_mfma_f32_16x16x32_bf16(fq, sl, acc[ni], 0, 0, 0);
    }
  }
  float onwv[4];
#pragma unroll
  for (int ni = 0; ni < 4; ni++) onwv[ni] = onw[ni * 16 + (lane & 15)];
#pragma unroll
  for (int r = 0; r < 4; r++) {
    int t = w * 16 + (lane >> 4) * 4 + r;
    float o[4];
#pragma unroll
    for (int ni = 0; ni < 4; ni++) {
      int e = ni * 16 + (lane & 15);
      o[ni] = obuf[(size_t)bh * 65536 + (size_t)(t0c + t) * 64 + e] + acc[ni][r];
    }
    float ss = o[0] * o[0] + o[1] * o[1] + o[2] * o[2] + o[3] * o[3];
    ss += __shfl_xor(ss, 1);
    ss += __shfl_xor(ss, 2);
    ss += __shfl_xor(ss, 4);
    ss += __shfl_xor(ss, 8);
    float rinv = rsqrtf(ss * (1.f / 64.f) + 1e-6f);
    size_t gbase = ((size_t)(b * 1024 + t0c + t)) * 1024 + h * 64;
#pragma unroll
    for (int ni = 0; ni < 4; ni++) {
      int e = ni * 16 + (lane & 15);
      float on = o[ni] * rinv * onwv[ni];
      float sil = on / (1.f + expf(-on));
      robuf[gbase + e] = g[gbase + e] * sil;
    }
  }
}

// ---------------------------------------------------------------------------
extern "C" void kernel_launch(void* const* d_in, const int* in_sizes, int n_in,
                              void* d_out, int out_size, void* d_ws, size_t ws_size,
                              hipStream_t stream) {
  (void)in_sizes; (void)n_in; (void)out_size; (void)ws_size;
  const float* x    = (const float*)d_in[0];
  const float* Wq   = (const float*)d_in[1];
  const float* Wk   = (const float*)d_in[2];
  const float* Wv   = (const float*)d_in[3];
  const float* Wg   = (const float*)d_in[4];
  const float* Wo   = (const float*)d_in[5];
  const float* bw   = (const float*)d_in[6];
  const float* bb   = (const float*)d_in[7];
  const float* gkw  = (const float*)d_in[8];
  const float* gkb  = (const float*)d_in[9];
  const float* qcw  = (const float*)d_in[10];
  const float* qcb  = (const float*)d_in[11];
  const float* kcw  = (const float*)d_in[12];
  const float* kcb  = (const float*)d_in[13];
  const float* vcw  = (const float*)d_in[14];
  const float* vcb  = (const float*)d_in[15];
  const float* A_log= (const float*)d_in[16];
  const float* Dp   = (const float*)d_in[17];
  const float* dtb  = (const float*)d_in[18];
  const float* onw  = (const float*)d_in[19];

  char* ws = (char*)d_ws;
  const size_t MB = 1024 * 1024;
  __bf16* Wq_h = (__bf16*)(ws + 8 * MB);
  __bf16* Wq_l = (__bf16*)(ws + 10 * MB);
  __bf16* Wk_h = (__bf16*)(ws + 12 * MB);
  __bf16* Wk_l = (__bf16*)(ws + 14 * MB);
  __bf16* Wv_h = (__bf16*)(ws + 16 * MB);
  __bf16* Wv_l = (__bf16*)(ws + 18 * MB);
  __bf16* Wg_h = (__bf16*)(ws + 20 * MB);
  __bf16* Wg_l = (__bf16*)(ws + 22 * MB);
  __bf16* Wo_h = (__bf16*)(ws + 24 * MB);
  __bf16* Wo_l = (__bf16*)(ws + 26 * MB);
  float* q_pre = (float*)(ws + 28 * MB);
  float* k_pre = (float*)(ws + 36 * MB);
  float* v_pre = (float*)(ws + 44 * MB);
  float* g_buf = (float*)(ws + 52 * MB);
  float* qrb   = (float*)(ws + 0);
  float* krb   = (float*)(ws + 8 * MB);
  float* vr    = (float*)(ws + 16 * MB);
  float* obuf  = v_pre;
  float* AcF   = (float*)(ws + 28 * MB);
  float* BcTF  = (float*)(ws + 36 * MB);
  float* S0TF  = (float*)(ws + 0);
  float* QeffF = (float*)(ws + 16 * MB);
  float* robuf = (float*)(ws + 8 * MB);
  float* alphaB = (float*)(ws + 60 * MB);
  float* betaB  = (float*)(ws + 60 * MB + 128 * 1024);
  float4* aux   = (float4*)(ws + 60 * MB + 256 * 1024);
  float* gcF    = (float*)(ws + 60 * MB + 768 * 1024);
  float* out    = (float*)d_out;

  k_transp_split<<<dim3(16, 16, 5), 256, 0, stream>>>(
      Wq, Wk, Wv, Wg, Wo,
      Wq_h, Wk_h, Wv_h, Wg_h, Wo_h,
      Wq_l, Wk_l, Wv_l, Wg_l, Wo_l);
  k_gates<<<2048, 256, 0, stream>>>(x, bw, bb, gkw, gkb, A_log, dtb, alphaB, betaB);
  k_gemm3f<<<dim3(8, 16, 4), 256, 0, stream>>>(
      x,
      Wq_h, Wk_h, Wv_h, Wg_h,
      Wq_l, Wk_l, Wv_l, Wg_l,
      q_pre, k_pre, v_pre, g_buf, 1024, 1024);
  k_cra<<<8192, 256, 0, stream>>>(q_pre, k_pre, v_pre,
                                  qcw, qcb, kcw, kcb, vcw, vcb,
                                  alphaB, betaB, Dp, qrb, krb, vr, aux);
  k_scanA<<<512, 256, 0, stream>>>(qrb, krb, vr, aux, obuf, AcF, BcTF, QeffF, gcF);
  k_scanB<<<128, 256, 0, stream>>>(AcF, BcTF, gcF, S0TF);
  k_scanCn<<<512, 256, 0, stream>>>(S0TF, QeffF, obuf, g_buf, onw, robuf);
  k_gemm3f<<<dim3(8, 16, 1), 256, 0, stream>>>(
      robuf,
      Wo_h, Wo_h, Wo_h, Wo_h,
      Wo_l, Wo_l, Wo_l, Wo_l,
      out, out, out, out, 1024, 1024);
}

// Round 11
// 320.874 us; speedup vs baseline: 1.3097x; 1.0001x over previous
//
#include <hip/hip_runtime.h>
#include <hip/hip_bf16.h>
#include <cstdint>

// Problem constants
#define T_LEN 1024
#define HIDN  1024
#define NH    16
#define DHD   64

typedef __bf16 bf16x8 __attribute__((ext_vector_type(8)));
typedef float  f32x4  __attribute__((ext_vector_type(4)));

__device__ inline void split8(float4 x0, float4 x1, uint4& hi, uint4& lo) {
  union { __bf16 h[8]; uint4 u; } ph, pl;
  float v[8] = {x0.x, x0.y, x0.z, x0.w, x1.x, x1.y, x1.z, x1.w};
#pragma unroll
  for (int j = 0; j < 8; j++) {
    __bf16 h = (__bf16)v[j];
    ph.h[j] = h;
    pl.h[j] = (__bf16)(v[j] - (float)h);
  }
  hi = ph.u; lo = pl.u;
}

// ---------------------------------------------------------------------------
// K2: transpose 1024x1024 f32 W[k][n] -> bf16 hi/lo Wt[n][k] (5 weights via z)
// ---------------------------------------------------------------------------
__global__ __launch_bounds__(256) void k_transp_split(
    const float* __restrict__ W0, const float* __restrict__ W1,
    const float* __restrict__ W2, const float* __restrict__ W3,
    const float* __restrict__ W4,
    __bf16* __restrict__ H0, __bf16* __restrict__ H1, __bf16* __restrict__ H2,
    __bf16* __restrict__ H3, __bf16* __restrict__ H4,
    __bf16* __restrict__ L0, __bf16* __restrict__ L1, __bf16* __restrict__ L2,
    __bf16* __restrict__ L3, __bf16* __restrict__ L4) {
  const float* W; __bf16* Th; __bf16* Tl;
  switch (blockIdx.z) {
    case 0: W = W0; Th = H0; Tl = L0; break;
    case 1: W = W1; Th = H1; Tl = L1; break;
    case 2: W = W2; Th = H2; Tl = L2; break;
    case 3: W = W3; Th = H3; Tl = L3; break;
    default: W = W4; Th = H4; Tl = L4; break;
  }
  __shared__ float tile[64][65];
  int tid = threadIdx.x;
  int r0 = tid >> 4;          // 0..15
  int c0 = (tid & 15) * 4;    // 0..60
  int kbase = blockIdx.y * 64, nbase = blockIdx.x * 64;
#pragma unroll
  for (int rr = 0; rr < 4; rr++) {
    int r = r0 + rr * 16;
    float4 v = *(const float4*)(W + (size_t)(kbase + r) * 1024 + nbase + c0);
    tile[r][c0 + 0] = v.x; tile[r][c0 + 1] = v.y;
    tile[r][c0 + 2] = v.z; tile[r][c0 + 3] = v.w;
  }
  __syncthreads();
#pragma unroll
  for (int rr = 0; rr < 4; rr++) {
    int n = r0 + rr * 16;
    union { __bf16 h[4]; unsigned long long u; } ph, pl;
#pragma unroll
    for (int j = 0; j < 4; j++) {
      float v = tile[c0 + j][n];
      __bf16 h = (__bf16)v;
      ph.h[j] = h;
      pl.h[j] = (__bf16)(v - (float)h);
    }
    *(unsigned long long*)(Th + (size_t)(nbase + n) * 1024 + kbase + c0) = ph.u;
    *(unsigned long long*)(Tl + (size_t)(nbase + n) * 1024 + kbase + c0) = pl.u;
  }
}

// ---------------------------------------------------------------------------
// K3: split-precision GEMM, A fp32 (inline hi/lo split), B pre-split bf16.
// C = Ah*Bh + Al*Bh + Ah*Bl. 128x128 tile, BK=32, 4 waves.
// ---------------------------------------------------------------------------
#define LDT 40
__global__ __launch_bounds__(256) void k_gemm3f(
    const float* __restrict__ Af,
    const __bf16* __restrict__ Bh0, const __bf16* __restrict__ Bh1,
    const __bf16* __restrict__ Bh2, const __bf16* __restrict__ Bh3,
    const __bf16* __restrict__ Bl0, const __bf16* __restrict__ Bl1,
    const __bf16* __restrict__ Bl2, const __bf16* __restrict__ Bl3,
    float* __restrict__ C0, float* __restrict__ C1,
    float* __restrict__ C2, float* __restrict__ C3,
    int Kdim, int Ncols) {
  const __bf16* Bh; const __bf16* Bl; float* C;
  switch (blockIdx.z) {
    case 0: Bh = Bh0; Bl = Bl0; C = C0; break;
    case 1: Bh = Bh1; Bl = Bl1; C = C1; break;
    case 2: Bh = Bh2; Bl = Bl2; C = C2; break;
    default: Bh = Bh3; Bl = Bl3; C = C3; break;
  }
  __shared__ __bf16 Ash[128 * LDT];
  __shared__ __bf16 Asl[128 * LDT];
  __shared__ __bf16 Bsh[128 * LDT];
  __shared__ __bf16 Bsl[128 * LDT];
  const int tid = threadIdx.x;
  const int lane = tid & 63;
  const int wave = tid >> 6;
  const int wr = wave >> 1, wc = wave & 1;
  const int rowA0 = blockIdx.y * 128;
  const int colB0 = blockIdx.x * 128;
  const int sseg = tid & 3;
  const int srow0 = tid >> 2;
  const int srow1 = srow0 + 64;

  f32x4 acc[4][4] = {};

  for (int k0 = 0; k0 < Kdim; k0 += 32) {
    size_t a0 = (size_t)(rowA0 + srow0) * Kdim + k0 + sseg * 8;
    size_t a1 = (size_t)(rowA0 + srow1) * Kdim + k0 + sseg * 8;
    size_t b0 = (size_t)(colB0 + srow0) * Kdim + k0 + sseg * 8;
    size_t b1 = (size_t)(colB0 + srow1) * Kdim + k0 + sseg * 8;
    float4 a00 = *(const float4*)(Af + a0);
    float4 a01 = *(const float4*)(Af + a0 + 4);
    float4 a10 = *(const float4*)(Af + a1);
    float4 a11 = *(const float4*)(Af + a1 + 4);
    uint4 rbh0 = *(const uint4*)(Bh + b0);
    uint4 rbh1 = *(const uint4*)(Bh + b1);
    uint4 rbl0 = *(const uint4*)(Bl + b0);
    uint4 rbl1 = *(const uint4*)(Bl + b1);
    uint4 rah0, ral0, rah1, ral1;
    split8(a00, a01, rah0, ral0);
    split8(a10, a11, rah1, ral1);
    __syncthreads();
    *(uint4*)&Ash[srow0 * LDT + sseg * 8] = rah0;
    *(uint4*)&Ash[srow1 * LDT + sseg * 8] = rah1;
    *(uint4*)&Asl[srow0 * LDT + sseg * 8] = ral0;
    *(uint4*)&Asl[srow1 * LDT + sseg * 8] = ral1;
    *(uint4*)&Bsh[srow0 * LDT + sseg * 8] = rbh0;
    *(uint4*)&Bsh[srow1 * LDT + sseg * 8] = rbh1;
    *(uint4*)&Bsl[srow0 * LDT + sseg * 8] = rbl0;
    *(uint4*)&Bsl[srow1 * LDT + sseg * 8] = rbl1;
    __syncthreads();
    bf16x8 afh[4], afl[4], bfh[4], bfl[4];
#pragma unroll
    for (int mi = 0; mi < 4; mi++) {
      int off = (wr * 64 + mi * 16 + (lane & 15)) * LDT + (lane >> 4) * 8;
      afh[mi] = *(const bf16x8*)&Ash[off];
      afl[mi] = *(const bf16x8*)&Asl[off];
    }
#pragma unroll
    for (int ni = 0; ni < 4; ni++) {
      int off = (wc * 64 + ni * 16 + (lane & 15)) * LDT + (lane >> 4) * 8;
      bfh[ni] = *(const bf16x8*)&Bsh[off];
      bfl[ni] = *(const bf16x8*)&Bsl[off];
    }
#pragma unroll
    for (int mi = 0; mi < 4; mi++)
#pragma unroll
      for (int ni = 0; ni < 4; ni++) {
        acc[mi][ni] = __builtin_amdgcn_mfma_f32_16x16x32_bf16(afh[mi], bfh[ni], acc[mi][ni], 0, 0, 0);
        acc[mi][ni] = __builtin_amdgcn_mfma_f32_16x16x32_bf16(afl[mi], bfh[ni], acc[mi][ni], 0, 0, 0);
        acc[mi][ni] = __builtin_amdgcn_mfma_f32_16x16x32_bf16(afh[mi], bfl[ni], acc[mi][ni], 0, 0, 0);
      }
  }
#pragma unroll
  for (int mi = 0; mi < 4; mi++)
#pragma unroll
    for (int ni = 0; ni < 4; ni++) {
      int col = colB0 + wc * 64 + ni * 16 + (lane & 15);
#pragma unroll
      for (int r = 0; r < 4; r++) {
        int row = rowA0 + wr * 64 + mi * 16 + (lane >> 4) * 4 + r;
        C[(size_t)row * Ncols + col] = acc[mi][ni][r];
      }
    }
}

// ---------------------------------------------------------------------------
// K4: gates (standalone; coalesced weight reads)
// ---------------------------------------------------------------------------
__global__ __launch_bounds__(256) void k_gates(
    const float* __restrict__ x, const float* __restrict__ bw,
    const float* __restrict__ bb, const float* __restrict__ gkw,
    const float* __restrict__ gkb, const float* __restrict__ A_log,
    const float* __restrict__ dt_bias,
    float* __restrict__ alphaB, float* __restrict__ betaB) {
  const int bt = blockIdx.x;
  const int tid = threadIdx.x;
  const int h = tid & 15;
  const int chunk = tid >> 4;
  const float* xr = x + (size_t)bt * HIDN;
  float d1 = 0.f, d2 = 0.f;
#pragma unroll 8
  for (int j = 0; j < 64; j++) {
    int k = chunk * 64 + j;
    float xv = xr[k];
    d1 += xv * bw[k * 16 + h];
    d2 += xv * gkw[k * 16 + h];
  }
  __shared__ float p1[16][16], p2[16][16];
  p1[chunk][h] = d1; p2[chunk][h] = d2;
  __syncthreads();
  if (tid < 16) {
    float s1 = 0.f, s2 = 0.f;
#pragma unroll
    for (int c = 0; c < 16; c++) { s1 += p1[c][tid]; s2 += p2[c][tid]; }
    float beta = 1.f / (1.f + expf(-(s1 + bb[tid])));
    float z = s2 + gkb[tid] + dt_bias[tid];
    float sp = fmaxf(z, 0.f) + log1pf(expf(-fabsf(z)));
    float alpha = expf(-expf(A_log[tid]) * sp);
    alphaB[(size_t)bt * 16 + tid] = alpha;
    betaB[(size_t)bt * 16 + tid] = beta;
  }
}

// ---------------------------------------------------------------------------
// K8a-fused: phase0 = conv(K=4)+SiLU -> RoPE -> L2norm (direct from pre-
// projection tensors, rolling tap registers), then WY-form per-chunk work.
// 4 waves; wave w handles t-rows [w*16, w*16+16). Wave0 also does the decay
// prefix scan from alphaB/betaB. Outputs: O1 fp32, BcT fp32, Ac bf16,
// Qeff bf16, gc.
// ---------------------------------------------------------------------------
__global__ __launch_bounds__(256) void k_scanA(
    const float* __restrict__ qp, const float* __restrict__ kp,
    const float* __restrict__ vp,
    const float* __restrict__ qcw, const float* __restrict__ qcb,
    const float* __restrict__ kcw, const float* __restrict__ kcb,
    const float* __restrict__ vcw, const float* __restrict__ vcb,
    const float* __restrict__ alphaB, const float* __restrict__ betaB,
    const float* __restrict__ Dp,
    float* __restrict__ O1, __bf16* __restrict__ AcB,
    float* __restrict__ BcTF, __bf16* __restrict__ QeffB,
    float* __restrict__ gcF) {
  const int bid = blockIdx.x;
  const int bh = bid >> 4, c = bid & 15;
  const int b = bh >> 4, h = bh & 15;
  const int t0 = c * 64;
  const int tid = threadIdx.x;
  const int w = tid >> 6, lane = tid & 63;

  __shared__ __bf16 q_b[64 * 72];
  __shared__ __bf16 k_b[64 * 72];
  __shared__ __bf16 kT_b[64 * 72];
  __shared__ __bf16 C_b[64 * 72];
  __shared__ __bf16 U0T[64 * 72];
  __shared__ __bf16 WT[64 * 72];
  __shared__ float  vS[64 * 64];
  __shared__ float  MTf[64 * 68];
  __shared__ float  lgS[64], pvS[64], beS[64], awS[64], enS[64];

  // ---- phase 0: conv + silu + rope + l2norm, rolling taps ----
  {
    const int cch = h * 64 + lane;
    const size_t bbase = ((size_t)b << 20) + cch;   // b*1024*1024 + cch
    const float* qpb = qp + bbase;
    const float* kpb = kp + bbase;
    const float* vpb = vp + bbase;
    float4 wq = *(const float4*)(qcw + (size_t)cch * 4);
    float4 wk = *(const float4*)(kcw + (size_t)cch * 4);
    float4 wv = *(const float4*)(vcw + (size_t)cch * 4);
    const float bq = qcb[cch], bk = kcb[cch], bv = vcb[cch];
    const float Dh = Dp[h];
    const int tstart = t0 + w * 16;
    float xq3 = (tstart >= 3) ? qpb[(size_t)(tstart - 3) * 1024] : 0.f;
    float xq2 = (tstart >= 2) ? qpb[(size_t)(tstart - 2) * 1024] : 0.f;
    float xq1 = (tstart >= 1) ? qpb[(size_t)(tstart - 1) * 1024] : 0.f;
    float xk3 = (tstart >= 3) ? kpb[(size_t)(tstart - 3) * 1024] : 0.f;
    float xk2 = (tstart >= 2) ? kpb[(size_t)(tstart - 2) * 1024] : 0.f;
    float xk1 = (tstart >= 1) ? kpb[(size_t)(tstart - 1) * 1024] : 0.f;
    float xv3 = (tstart >= 3) ? vpb[(size_t)(tstart - 3) * 1024] : 0.f;
    float xv2 = (tstart >= 2) ? vpb[(size_t)(tstart - 2) * 1024] : 0.f;
    float xv1 = (tstart >= 1) ? vpb[(size_t)(tstart - 1) * 1024] : 0.f;
    const int i = lane & 31;
    const float fr = expf(-(float)(2 * (i & 15)) * (9.210340371976184f / 32.f));
#pragma unroll
    for (int ii = 0; ii < 16; ii++) {
      const int tg = tstart + ii;
      float xq0 = qpb[(size_t)tg * 1024];
      float xk0 = kpb[(size_t)tg * 1024];
      float xv0 = vpb[(size_t)tg * 1024];
      float aq = bq + wq.x * xq3 + wq.y * xq2 + wq.z * xq1 + wq.w * xq0;
      float ak = bk + wk.x * xk3 + wk.y * xk2 + wk.z * xk1 + wk.w * xk0;
      float av = bv + wv.x * xv3 + wv.y * xv2 + wv.z * xv1 + wv.w * xv0;
      float yq = aq / (1.f + expf(-aq));
      float yk = ak / (1.f + expf(-ak));
      float yv = av / (1.f + expf(-av));
      // rope
      float ang = (float)tg * fr;
      float cv = cosf(ang), sv = sinf(ang);
      float q1 = __shfl(yq, 2 * i), q2 = __shfl(yq, 2 * i + 1);
      float k1 = __shfl(yk, 2 * i), k2 = __shfl(yk, 2 * i + 1);
      float qo = (lane < 32) ? (q1 * cv - q2 * sv) : (q1 * sv + q2 * cv);
      float ko = (lane < 32) ? (k1 * cv - k2 * sv) : (k1 * sv + k2 * cv);
      // l2 norm
      float qs = qo * qo, ks2 = ko * ko;
#pragma unroll
      for (int m = 1; m < 64; m <<= 1) { qs += __shfl_xor(qs, m); ks2 += __shfl_xor(ks2, m); }
      float qn = qo * rsqrtf(qs + 1e-6f);
      float kn = ko * rsqrtf(ks2 + 1e-6f);
      float dq = qn * kn;
#pragma unroll
      for (int m = 1; m < 64; m <<= 1) dq += __shfl_xor(dq, m);
      const int tl = w * 16 + ii;
      q_b[tl * 72 + lane] = (__bf16)qn;
      k_b[tl * 72 + lane] = (__bf16)kn;
      vS[tl * 64 + lane] = yv;
      if (lane == 0) awS[tl] = Dh * dq;
      xq3 = xq2; xq2 = xq1; xq1 = xq0;
      xk3 = xk2; xk2 = xk1; xk1 = xk0;
      xv3 = xv2; xv2 = xv1; xv1 = xv0;
    }
  }
  // wave0: decay prefix scan from gates output
  if (w == 0) {
    size_t gi = (size_t)(b * 1024 + t0 + lane) * 16 + h;
    float alpha = alphaB[gi];
    float beta = betaB[gi];
    float lg = logf(alpha);
#pragma unroll
    for (int off = 1; off < 64; off <<= 1) {
      float tv = __shfl_up(lg, off);
      if (lane >= off) lg += tv;
    }
    float pv = __shfl_up(lg, 1);
    if (lane == 0) pv = 0.f;
    float lgTot = __shfl(lg, 63);
    lgS[lane] = lg; pvS[lane] = pv; beS[lane] = beta;
    enS[lane] = expf(lgTot - lg);
    if (lane == 0) gcF[bid] = expf(lgTot);
  }
  __syncthreads();

  // ---- phase 2: KK->MT and QK->C, mi = w ----
  {
    const int mi = w;
#pragma unroll
    for (int ni = 0; ni < 4; ni++) {
      f32x4 akk = {0.f, 0.f, 0.f, 0.f};
      f32x4 aqk = {0.f, 0.f, 0.f, 0.f};
#pragma unroll
      for (int ks = 0; ks < 2; ks++) {
        bf16x8 fa_k = *(const bf16x8*)&k_b[(mi * 16 + (lane & 15)) * 72 + ks * 32 + (lane >> 4) * 8];
        bf16x8 fa_q = *(const bf16x8*)&q_b[(mi * 16 + (lane & 15)) * 72 + ks * 32 + (lane >> 4) * 8];
        bf16x8 fb_k = *(const bf16x8*)&k_b[(ni * 16 + (lane & 15)) * 72 + ks * 32 + (lane >> 4) * 8];
        akk = __builtin_amdgcn_mfma_f32_16x16x32_bf16(fa_k, fb_k, akk, 0, 0, 0);
        aqk = __builtin_amdgcn_mfma_f32_16x16x32_bf16(fa_q, fb_k, aqk, 0, 0, 0);
      }
#pragma unroll
      for (int r = 0; r < 4; r++) {
        int row = mi * 16 + (lane >> 4) * 4 + r;
        int col = ni * 16 + (lane & 15);
        float mt = 0.f, cv = 0.f;
        if (row > col) {
          mt = beS[row] * expf(lgS[row] - lgS[col]) * akk[r];
          cv = expf(pvS[row] - lgS[col]) * aqk[r];
        }
        MTf[col * 68 + row] = mt;
        C_b[row * 72 + col] = (__bf16)cv;
      }
    }
  }
  __syncthreads();

  // ---- phase 3+4: wave2 builds scaled K^T; waves 0,1 run the two solves ----
  if (w == 2) {
#pragma unroll
    for (int t8 = 0; t8 < 8; t8++) {
      union { __bf16 h[8]; uint4 u; } pt;
#pragma unroll
      for (int q = 0; q < 8; q++) {
        int t = t8 * 8 + q;
        pt.h[q] = (__bf16)((float)k_b[t * 72 + lane] * enS[t]);
      }
      *(uint4*)&kT_b[lane * 72 + t8 * 8] = pt.u;
    }
  }
  if (w < 2) {
    float u[64];
    if (w == 0) {
#pragma unroll
      for (int j = 0; j < 64; j++) u[j] = beS[j] * vS[j * 64 + lane];
    } else {
#pragma unroll
      for (int j = 0; j < 64; j++) u[j] = beS[j] * expf(lgS[j]) * (float)k_b[j * 72 + lane];
    }
    __bf16* dst = (w == 0) ? U0T : WT;
#pragma unroll
    for (int j = 0; j < 64; j++) {
      dst[lane * 72 + j] = (__bf16)u[j];
      float uj = u[j];
#pragma unroll
      for (int g = (j >> 4); g < 4; g++) {
#pragma unroll
        for (int q4 = 0; q4 < 4; q4++) {
          const float4 m4 = *(const float4*)&MTf[j * 68 + g * 16 + q4 * 4];
          u[g * 16 + q4 * 4 + 0] -= m4.x * uj;
          u[g * 16 + q4 * 4 + 1] -= m4.y * uj;
          u[g * 16 + q4 * 4 + 2] -= m4.z * uj;
          u[g * 16 + q4 * 4 + 3] -= m4.w * uj;
        }
      }
    }
  }
  __syncthreads();

  // ---- phase 5: output products, split across 4 waves ----
  size_t cb = (size_t)bid * 4096;
  const int mi0 = (w >> 1) * 2;
  if ((w & 1) == 0) {
#pragma unroll
    for (int mm = 0; mm < 2; mm++) {
      int mi = mi0 + mm;
#pragma unroll
      for (int ni = 0; ni < 4; ni++) {
        f32x4 ab = {0.f, 0.f, 0.f, 0.f};
        f32x4 aa = {0.f, 0.f, 0.f, 0.f};
#pragma unroll
        for (int ks = 0; ks < 2; ks++) {
          int aoff = (mi * 16 + (lane & 15)) * 72 + ks * 32 + (lane >> 4) * 8;
          int boff = (ni * 16 + (lane & 15)) * 72 + ks * 32 + (lane >> 4) * 8;
          bf16x8 fu = *(const bf16x8*)&U0T[aoff];
          bf16x8 fkm = *(const bf16x8*)&kT_b[aoff];
          bf16x8 fkn = *(const bf16x8*)&kT_b[boff];
          bf16x8 fw = *(const bf16x8*)&WT[boff];
          ab = __builtin_amdgcn_mfma_f32_16x16x32_bf16(fu, fkn, ab, 0, 0, 0);
          aa = __builtin_amdgcn_mfma_f32_16x16x32_bf16(fkm, fw, aa, 0, 0, 0);
        }
#pragma unroll
        for (int r = 0; r < 4; r++) {
          int row = mi * 16 + (lane >> 4) * 4 + r;
          int col = ni * 16 + (lane & 15);
          BcTF[cb + row * 64 + col] = ab[r];
          AcB[cb + row * 64 + col] = (__bf16)aa[r];
        }
      }
    }
  } else {
#pragma unroll
    for (int mm = 0; mm < 2; mm++) {
      int mi = mi0 + mm;
#pragma unroll
      for (int ni = 0; ni < 4; ni++) {
        f32x4 ao = {0.f, 0.f, 0.f, 0.f};
        f32x4 ac = {0.f, 0.f, 0.f, 0.f};
#pragma unroll
        for (int ks = 0; ks < 2; ks++) {
          int aoff = (mi * 16 + (lane & 15)) * 72 + ks * 32 + (lane >> 4) * 8;
          int boff = (ni * 16 + (lane & 15)) * 72 + ks * 32 + (lane >> 4) * 8;
          bf16x8 fc = *(const bf16x8*)&C_b[aoff];
          bf16x8 fu = *(const bf16x8*)&U0T[boff];
          bf16x8 fw = *(const bf16x8*)&WT[boff];
          ao = __builtin_amdgcn_mfma_f32_16x16x32_bf16(fc, fu, ao, 0, 0, 0);
          ac = __builtin_amdgcn_mfma_f32_16x16x32_bf16(fc, fw, ac, 0, 0, 0);
        }
#pragma unroll
        for (int r = 0; r < 4; r++) {
          int t = mi * 16 + (lane >> 4) * 4 + r;
          int col = ni * 16 + (lane & 15);
          O1[(size_t)bh * 65536 + (size_t)(t0 + t) * 64 + col] =
              ao[r] + awS[t] * vS[t * 64 + col];
          QeffB[cb + t * 64 + col] =
              (__bf16)(expf(pvS[t]) * (float)q_b[t * 72 + col] - ac[r]);
        }
      }
    }
  }
}

// ---------------------------------------------------------------------------
// K8b: serial state carry, row-parallel: grid 128 = (bh, e-group of 16 rows).
// Ac now bf16 in global (same rounding as the old in-kernel conversion).
// ---------------------------------------------------------------------------
__global__ __launch_bounds__(256) void k_scanB(
    const __bf16* __restrict__ AcB, const float* __restrict__ BcTF,
    const float* __restrict__ gcF, float* __restrict__ S0TF) {
  const int bid = blockIdx.x;           // bh*4 + eg
  const int bh = bid >> 2, eg = bid & 3;
  const int e0 = eg * 16;
  const int tid = threadIdx.x;
  const int w = tid >> 6, lane = tid & 63;
  const int er = tid >> 2, seg = (tid & 3) * 16;     // Ac staging (64 rows x 64)
  const int er2 = tid >> 4, seg2 = (tid & 15) * 4;   // S-part staging (16 x 64)
  __shared__ float STf[16 * 68];
  __shared__ __bf16 Sh[16 * 72], Sl[16 * 72], Ac_b[64 * 72];
  *(float4*)&STf[er2 * 68 + seg2] = make_float4(0.f, 0.f, 0.f, 0.f);
  __syncthreads();

  size_t cbase = (size_t)bh * 16 * 4096;
  // prologue: prefetch chunk 0
  uint4 acR0, acR1;
  float bctR[4];
  acR0 = *(const uint4*)&AcB[cbase + er * 64 + seg];
  acR1 = *(const uint4*)&AcB[cbase + er * 64 + seg + 8];
#pragma unroll
  for (int r = 0; r < 4; r++)
    bctR[r] = BcTF[cbase + (size_t)(e0 + (lane >> 4) * 4 + r) * 64 + w * 16 + (lane & 15)];

  for (int c = 0; c < 16; c++) {
    size_t cb = cbase + (size_t)c * 4096;
    // stage S-part -> Sh/Sl, emit S0T rows e0..e0+15
    {
      float4 s = *(const float4*)&STf[er2 * 68 + seg2];
      *(float4*)&S0TF[cb + (size_t)(e0 + er2) * 64 + seg2] = s;
      union { __bf16 h[4]; unsigned long long u; } ph, pl;
      float sv[4] = {s.x, s.y, s.z, s.w};
#pragma unroll
      for (int q = 0; q < 4; q++) {
        __bf16 hv = (__bf16)sv[q];
        ph.h[q] = hv;
        pl.h[q] = (__bf16)(sv[q] - (float)hv);
      }
      *(unsigned long long*)&Sh[er2 * 72 + seg2] = ph.u;
      *(unsigned long long*)&Sl[er2 * 72 + seg2] = pl.u;
    }
    // stage Ac regs -> LDS (already bf16)
    *(uint4*)&Ac_b[er * 72 + seg] = acR0;
    *(uint4*)&Ac_b[er * 72 + seg + 8] = acR1;
    float gC = gcF[bh * 16 + c];
    __syncthreads();

    // prefetch chunk c+1 (stays in flight across the MFMA)
    uint4 acN0 = acR0, acN1 = acR1;
    float bctN[4];
    if (c < 15) {
      size_t nb = cb + 4096;
      acN0 = *(const uint4*)&AcB[nb + er * 64 + seg];
      acN1 = *(const uint4*)&AcB[nb + er * 64 + seg + 8];
#pragma unroll
      for (int r = 0; r < 4; r++)
        bctN[r] = BcTF[nb + (size_t)(e0 + (lane >> 4) * 4 + r) * 64 + w * 16 + (lane & 15)];
    } else {
#pragma unroll
      for (int r = 0; r < 4; r++) bctN[r] = bctR[r];
    }

    // MFMA: wave w owns output cols d in [w*16, w*16+16)
    f32x4 acc = {0.f, 0.f, 0.f, 0.f};
#pragma unroll
    for (int ks = 0; ks < 2; ks++) {
      int aoff = (lane & 15) * 72 + ks * 32 + (lane >> 4) * 8;
      int boff = (w * 16 + (lane & 15)) * 72 + ks * 32 + (lane >> 4) * 8;
      bf16x8 ah = *(const bf16x8*)&Sh[aoff];
      bf16x8 al = *(const bf16x8*)&Sl[aoff];
      bf16x8 bb = *(const bf16x8*)&Ac_b[boff];
      acc = __builtin_amdgcn_mfma_f32_16x16x32_bf16(ah, bb, acc, 0, 0, 0);
      acc = __builtin_amdgcn_mfma_f32_16x16x32_bf16(al, bb, acc, 0, 0, 0);
    }
#pragma unroll
    for (int r = 0; r < 4; r++) {
      int e = (lane >> 4) * 4 + r;           // local row 0..15
      int d = w * 16 + (lane & 15);
      STf[e * 68 + d] = gC * STf[e * 68 + d] - acc[r] + bctR[r];
    }
    __syncthreads();
    acR0 = acN0; acR1 = acN1;
#pragma unroll
    for (int r = 0; r < 4; r++) bctR[r] = bctN[r];
  }
}

// ---------------------------------------------------------------------------
// K8c+K9 fused: O = O1 + Qeff@S0, then RMS-norm + silu gate -> robuf fp32.
// Qeff now bf16 in global (same rounding as the old in-kernel conversion).
// ---------------------------------------------------------------------------
__global__ __launch_bounds__(256) void k_scanCn(
    const float* __restrict__ S0TF, const __bf16* __restrict__ QeffB,
    const float* __restrict__ obuf, const float* __restrict__ g,
    const float* __restrict__ onw, float* __restrict__ robuf) {
  const int bid = blockIdx.x;
  const int bh = bid >> 4, c = bid & 15, t0c = c * 64;
  const int b = bh >> 4, h = bh & 15;
  const int tid = threadIdx.x;
  const int w = tid >> 6, lane = tid & 63;
  const int er = tid >> 2, seg = (tid & 3) * 16;
  size_t cb = (size_t)bid * 4096;
  __shared__ __bf16 Sh[64 * 72], Sl[64 * 72], Qb[64 * 72];
#pragma unroll
  for (int i = 0; i < 4; i++) {
    float4 s = *(const float4*)&S0TF[cb + er * 64 + seg + i * 4];
    union { __bf16 h[4]; unsigned long long u; } ph, pl;
    float sv[4] = {s.x, s.y, s.z, s.w};
#pragma unroll
    for (int q = 0; q < 4; q++) {
      __bf16 hv = (__bf16)sv[q];
      ph.h[q] = hv;
      pl.h[q] = (__bf16)(sv[q] - (float)hv);
    }
    *(unsigned long long*)&Sh[er * 72 + seg + i * 4] = ph.u;
    *(unsigned long long*)&Sl[er * 72 + seg + i * 4] = pl.u;
  }
  {
    uint4 qv0 = *(const uint4*)&QeffB[cb + er * 64 + seg];
    uint4 qv1 = *(const uint4*)&QeffB[cb + er * 64 + seg + 8];
    *(uint4*)&Qb[er * 72 + seg] = qv0;
    *(uint4*)&Qb[er * 72 + seg + 8] = qv1;
  }
  __syncthreads();
  f32x4 acc[4];
#pragma unroll
  for (int ni = 0; ni < 4; ni++) {
    acc[ni] = (f32x4){0.f, 0.f, 0.f, 0.f};
#pragma unroll
    for (int ks = 0; ks < 2; ks++) {
      int aoff = (w * 16 + (lane & 15)) * 72 + ks * 32 + (lane >> 4) * 8;
      int boff = (ni * 16 + (lane & 15)) * 72 + ks * 32 + (lane >> 4) * 8;
      bf16x8 fq = *(const bf16x8*)&Qb[aoff];
      bf16x8 sh = *(const bf16x8*)&Sh[boff];
      bf16x8 sl = *(const bf16x8*)&Sl[boff];
      acc[ni] = __builtin_amdgcn_mfma_f32_16x16x32_bf16(fq, sh, acc[ni], 0, 0, 0);
      acc[ni] = __builtin_amdgcn_mfma_f32_16x16x32_bf16(fq, sl, acc[ni], 0, 0, 0);
    }
  }
  float onwv[4];
#pragma unroll
  for (int ni = 0; ni < 4; ni++) onwv[ni] = onw[ni * 16 + (lane & 15)];
#pragma unroll
  for (int r = 0; r < 4; r++) {
    int t = w * 16 + (lane >> 4) * 4 + r;
    float o[4];
#pragma unroll
    for (int ni = 0; ni < 4; ni++) {
      int e = ni * 16 + (lane & 15);
      o[ni] = obuf[(size_t)bh * 65536 + (size_t)(t0c + t) * 64 + e] + acc[ni][r];
    }
    float ss = o[0] * o[0] + o[1] * o[1] + o[2] * o[2] + o[3] * o[3];
    ss += __shfl_xor(ss, 1);
    ss += __shfl_xor(ss, 2);
    ss += __shfl_xor(ss, 4);
    ss += __shfl_xor(ss, 8);
    float rinv = rsqrtf(ss * (1.f / 64.f) + 1e-6f);
    size_t gbase = ((size_t)(b * 1024 + t0c + t)) * 1024 + h * 64;
#pragma unroll
    for (int ni = 0; ni < 4; ni++) {
      int e = ni * 16 + (lane & 15);
      float on = o[ni] * rinv * onwv[ni];
      float sil = on / (1.f + expf(-on));
      robuf[gbase + e] = g[gbase + e] * sil;
    }
  }
}

// ---------------------------------------------------------------------------
extern "C" void kernel_launch(void* const* d_in, const int* in_sizes, int n_in,
                              void* d_out, int out_size, void* d_ws, size_t ws_size,
                              hipStream_t stream) {
  (void)in_sizes; (void)n_in; (void)out_size; (void)ws_size;
  const float* x    = (const float*)d_in[0];
  const float* Wq   = (const float*)d_in[1];
  const float* Wk   = (const float*)d_in[2];
  const float* Wv   = (const float*)d_in[3];
  const float* Wg   = (const float*)d_in[4];
  const float* Wo   = (const float*)d_in[5];
  const float* bw   = (const float*)d_in[6];
  const float* bb   = (const float*)d_in[7];
  const float* gkw  = (const float*)d_in[8];
  const float* gkb  = (const float*)d_in[9];
  const float* qcw  = (const float*)d_in[10];
  const float* qcb  = (const float*)d_in[11];
  const float* kcw  = (const float*)d_in[12];
  const float* kcb  = (const float*)d_in[13];
  const float* vcw  = (const float*)d_in[14];
  const float* vcb  = (const float*)d_in[15];
  const float* A_log= (const float*)d_in[16];
  const float* Dp   = (const float*)d_in[17];
  const float* dtb  = (const float*)d_in[18];
  const float* onw  = (const float*)d_in[19];

  char* ws = (char*)d_ws;
  const size_t MB = 1024 * 1024;
  // Layout:
  //  0.. 8: obuf (scanA O1; scanCn in)
  //  8..16: Wq hi/lo (dead after proj gemm) -> BcTF (scanA out, fp32)
  // 16..20: Wk_h -> QeffB (bf16) ; 20..24: Wk_l..(part) -> AcB (bf16)
  //   (full weight plan: Wq 8..12, Wk 12..16, Wv 16..20, Wg 20..24 — all
  //    dead after proj gemm, safe to overwrite by scanA outputs)
  // 24..28: Wo hi/lo (live to end)
  // 28..36: q_pre (scanA in) -> S0TF (scanB out, after scanA)
  // 36..44: k_pre (scanA in) -> robuf (scanCn out, after scanA)
  // 44..52: v_pre (scanA in)
  // 52..60: g_buf (live till scanCn)
  // 60+   : alphaB, betaB, gcF
  __bf16* Wq_h = (__bf16*)(ws + 8 * MB);
  __bf16* Wq_l = (__bf16*)(ws + 10 * MB);
  __bf16* Wk_h = (__bf16*)(ws + 12 * MB);
  __bf16* Wk_l = (__bf16*)(ws + 14 * MB);
  __bf16* Wv_h = (__bf16*)(ws + 16 * MB);
  __bf16* Wv_l = (__bf16*)(ws + 18 * MB);
  __bf16* Wg_h = (__bf16*)(ws + 20 * MB);
  __bf16* Wg_l = (__bf16*)(ws + 22 * MB);
  __bf16* Wo_h = (__bf16*)(ws + 24 * MB);
  __bf16* Wo_l = (__bf16*)(ws + 26 * MB);
  float* q_pre = (float*)(ws + 28 * MB);
  float* k_pre = (float*)(ws + 36 * MB);
  float* v_pre = (float*)(ws + 44 * MB);
  float* g_buf = (float*)(ws + 52 * MB);
  float* obuf  = (float*)(ws + 0);
  float* BcTF  = (float*)(ws + 8 * MB);
  __bf16* QeffB = (__bf16*)(ws + 16 * MB);
  __bf16* AcB   = (__bf16*)(ws + 20 * MB);
  float* S0TF  = (float*)(ws + 28 * MB);   // q_pre dead after scanA
  float* robuf = (float*)(ws + 36 * MB);   // k_pre dead after scanA
  float* alphaB = (float*)(ws + 60 * MB);
  float* betaB  = (float*)(ws + 60 * MB + 128 * 1024);
  float* gcF    = (float*)(ws + 60 * MB + 256 * 1024);
  float* out    = (float*)d_out;

  k_transp_split<<<dim3(16, 16, 5), 256, 0, stream>>>(
      Wq, Wk, Wv, Wg, Wo,
      Wq_h, Wk_h, Wv_h, Wg_h, Wo_h,
      Wq_l, Wk_l, Wv_l, Wg_l, Wo_l);
  k_gates<<<2048, 256, 0, stream>>>(x, bw, bb, gkw, gkb, A_log, dtb, alphaB, betaB);
  k_gemm3f<<<dim3(8, 16, 4), 256, 0, stream>>>(
      x,
      Wq_h, Wk_h, Wv_h, Wg_h,
      Wq_l, Wk_l, Wv_l, Wg_l,
      q_pre, k_pre, v_pre, g_buf, 1024, 1024);
  // fused conv+rope+norm + WY per-chunk work
  k_scanA<<<512, 256, 0, stream>>>(q_pre, k_pre, v_pre,
                                   qcw, qcb, kcw, kcb, vcw, vcb,
                                   alphaB, betaB, Dp,
                                   obuf, AcB, BcTF, QeffB, gcF);
  k_scanB<<<128, 256, 0, stream>>>(AcB, BcTF, gcF, S0TF);
  k_scanCn<<<512, 256, 0, stream>>>(S0TF, QeffB, obuf, g_buf, onw, robuf);
  k_gemm3f<<<dim3(8, 16, 1), 256, 0, stream>>>(
      robuf,
      Wo_h, Wo_h, Wo_h, Wo_h,
      Wo_l, Wo_l, Wo_l, Wo_l,
      out, out, out, out, 1024, 1024);
}